// Round 5
// baseline (1220.026 us; speedup 1.0000x reference)
//
#include <hip/hip_runtime.h>
#include <cstdint>

// FNet block on MI355X.
//   attn = Re(FFT2(x)) via bf16 MFMA matmuls + real-input quadrant symmetry:
//     GEMM1: T[r][0:512]=Tc, T[r][512:1024]=Ts   (M=32768, N=1024, K=768)
//     transpose_T: BtU[b][d][s]=Tc[s,d], BtV[b][d][s]=Ts[s,d]
//     GEMM_uv (fused, z=0..15): u[z][k][d] (cos) / v[z][k][d] (sin), M=2304(pad),N=512,K=4096
//     combine: attn[k,d]=u-v; [k,768-d]=u+v; [4096-k,d]=u+v; [4096-k,768-d]=u-v
//   LN1 -> out1 (bf16)
//   GEMM3: H = gelu(out1 @ W1 + b1)       (M=32768, N=3072, K=768)
//   GEMM4: y2 = H @ W2 + b2 + out1        (M=32768, N=768, K=3072)
//   LN2 in-place on d_out.
// GEMM core: 256x256 tile, BK=64, 8 waves, LDS 128 KiB double-buffer,
// global_load_lds(16B) staging, 2-deep prefetch, counted vmcnt(8), T2 swizzle.
// NEW (round 5): compute region split into 4 phases/K-tile (16 MFMA each,
// setprio-wrapped, sched_barrier-pinned) with one-phase-ahead ds_read prefetch
// — same barrier/STAGE skeleton as the round-4 kernel that passed (race-free).

typedef __attribute__((ext_vector_type(8))) short short8;
typedef __attribute__((ext_vector_type(4))) float f32x4;

__device__ __forceinline__ unsigned short f2b(float f) {
  union { float f; uint32_t u; } c; c.f = f;
  uint32_t u = c.u;
  u += 0x7FFFu + ((u >> 16) & 1u);   // round-to-nearest-even
  return (unsigned short)(u >> 16);
}
__device__ __forceinline__ float b2f(unsigned short h) {
  union { uint32_t u; float f; } c; c.u = ((uint32_t)h) << 16;
  return c.f;
}

// ---------------------------------------------------------------------------
// Fill / convert kernels (unchanged, verified)
// ---------------------------------------------------------------------------

__global__ __launch_bounds__(256) void f32_to_bf16_vec(
    const float* __restrict__ in, unsigned short* __restrict__ out) {
  long i = (long)blockIdx.x * 256 + threadIdx.x;   // element-of-4 index
  float4 v = reinterpret_cast<const float4*>(in)[i];
  ushort4 o;
  o.x = f2b(v.x); o.y = f2b(v.y); o.z = f2b(v.z); o.w = f2b(v.w);
  reinterpret_cast<ushort4*>(out)[i] = o;
}

// Bt1: (1024 x 768). Row j<512: cos(2*pi*j*n/768); row j>=512: sin(2*pi*(j-512)*n/768).
__global__ __launch_bounds__(256) void fill_bt1(unsigned short* __restrict__ Bt1) {
  int i = blockIdx.x * 256 + threadIdx.x;          // < 1024*768
  int j = i / 768;
  int n = i - j * 768;
  int jj = j & 511;
  int m = (jj * n) % 768;
  float ang = (float)m * (6.283185307179586f / 768.0f);
  Bt1[i] = f2b((j < 512) ? cosf(ang) : sinf(ang));
}

// Au[k][s] = cos(2*pi*k*s/4096), Av[k][s] = sin(...), k=0..2303 (padded), s=0..4095.
__global__ __launch_bounds__(256) void fill_auv(
    unsigned short* __restrict__ Au, unsigned short* __restrict__ Av) {
  long i = (long)blockIdx.x * 256 + threadIdx.x;   // < 2304*4096
  int k = (int)(i >> 12);
  int s = (int)(i & 4095);
  int mm = (k * s) & 4095;
  float ang = (float)mm * (6.283185307179586f / 4096.0f);
  Au[i] = f2b(cosf(ang));
  Av[i] = f2b(sinf(ang));
}

// out[c][r] = bf16(in[r][c]); R,C multiples of 32  (for W1, W2)
__global__ __launch_bounds__(256) void transpose_f32_to_bf16(
    const float* __restrict__ in, unsigned short* __restrict__ out, int R, int C) {
  __shared__ float tile[32][33];
  const int c0 = blockIdx.x * 32;
  const int r0 = blockIdx.y * 32;
  const int tx = threadIdx.x & 31;
  const int ty = threadIdx.x >> 5;   // 0..7
#pragma unroll
  for (int i = ty; i < 32; i += 8)
    tile[i][tx] = in[(long)(r0 + i) * C + c0 + tx];
  __syncthreads();
#pragma unroll
  for (int i = ty; i < 32; i += 8)
    out[(long)(c0 + i) * R + r0 + tx] = f2b(tile[tx][i]);
}

// BtUV[(d<512?0:HALF) + (b*512 + (d&511))*4096 + s] = T[(b*4096+s)*1024 + d]
__global__ __launch_bounds__(256) void transpose_T(
    const unsigned short* __restrict__ T, unsigned short* __restrict__ BtUV) {
  __shared__ unsigned short tile[32][33];
  const int s0 = blockIdx.x * 32;
  const int d0 = blockIdx.y * 32;
  const int b  = blockIdx.z;
  const int tx = threadIdx.x & 31;
  const int ty = threadIdx.x >> 5;   // 0..7
  const unsigned short* Tb = T + ((long)b * 4096 + s0) * 1024 + d0;
#pragma unroll
  for (int i = ty; i < 32; i += 8)
    tile[i][tx] = Tb[(long)i * 1024 + tx];       // tile[s_local][d_local]
  __syncthreads();
#pragma unroll
  for (int i = ty; i < 32; i += 8) {
    const int d = d0 + i;
    const long off = (d < 512) ? 0L : 16777216L;
    BtUV[off + ((long)b * 512 + (d & 511)) * 4096 + s0 + tx] = tile[tx][i];
  }
}

// ---------------------------------------------------------------------------
// GEMM256: C = A (MxK row-major bf16) @ Bt^T (Bt NxK row-major bf16)
// 256x256 tile, BK=64, 512 threads (8 waves, 2x4), per-wave 128x64 output.
// ---------------------------------------------------------------------------

template <int EPI>
__global__ __launch_bounds__(512, 2) void gemm256(
    const unsigned short* __restrict__ A, const unsigned short* __restrict__ Bt,
    const unsigned short* __restrict__ A2p, const unsigned short* __restrict__ Bt2p,
    int K, int lda, int ldb, long bBatch, long oBatch, int zSplit,
    float* __restrict__ outF, float* __restrict__ outF2,
    unsigned short* __restrict__ outB,
    const float* __restrict__ bias, const unsigned short* __restrict__ residB,
    int ldOut) {
  __shared__ __align__(16) unsigned short AsB[2][16384];   // [buf][256 rows][64 cols]
  __shared__ __align__(16) unsigned short BsB[2][16384];

  const int tid = threadIdx.x;
  const int lane = tid & 63;
  const int wid = tid >> 6;          // 0..7
  const int wm = wid >> 2;           // 0..1
  const int wn = wid & 3;            // 0..3

  int zz = blockIdx.z;
  const unsigned short* Ax = A;
  const unsigned short* Bx = Bt;
  float* oF = outF;
  if (EPI == 1 && zz >= zSplit) { Ax = A2p; Bx = Bt2p; oF = outF2; zz -= zSplit; }

  const unsigned short* Ab = Ax + (long)blockIdx.x * 256 * lda;
  const unsigned short* Bb = Bx + (long)zz * bBatch + (long)blockIdx.y * 256 * ldb;

  const int NT = K >> 6;             // number of BK=64 tiles (>= 2)

  // --- staging: one call = 8 gload_lds instrs/wave (4 A + 4 B), 64 KB total ---
  const int srow = (lane >> 3);                       // 0..7  (row within 8-row region)
  const int scolE = ((lane & 7) ^ (lane >> 3)) << 3;  // pre-swizzled source col (elems)
#define STAGE(buf, kt) do {                                                            \
    const unsigned short* As_ = Ab + (long)(kt) * 64;                                  \
    const unsigned short* Bs_ = Bb + (long)(kt) * 64;                                  \
    _Pragma("unroll")                                                                  \
    for (int i_ = 0; i_ < 4; ++i_) {                                                   \
      const int R_ = i_ * 8 + wid;                   /* region 0..31, wave-uniform */  \
      const int row_ = R_ * 8 + srow;                                                  \
      __builtin_amdgcn_global_load_lds(                                                \
        (const __attribute__((address_space(1))) void*)(As_ + (long)row_ * lda + scolE), \
        (__attribute__((address_space(3))) void*)(&AsB[buf][R_ * 512]), 16, 0, 0);     \
      __builtin_amdgcn_global_load_lds(                                                \
        (const __attribute__((address_space(1))) void*)(Bs_ + (long)row_ * ldb + scolE), \
        (__attribute__((address_space(3))) void*)(&BsB[buf][R_ * 512]), 16, 0, 0);     \
    } } while (0)

  // --- swizzled fragment reads (row&7 == lane&7 for all frag rows) ---
  const int fr = lane & 15;          // frag row within 16
  const int fkE = (lane >> 4) << 3;  // k-offset elems (0,8,16,24)
  const int fxor = (lane & 7) << 4;  // T2 swizzle XOR (lane-constant)

  f32x4 acc[8][4] = {};

  STAGE(0, 0);
  STAGE(1, 1);
  asm volatile("s_waitcnt vmcnt(8)" ::: "memory");
  __builtin_amdgcn_sched_barrier(0);
  __builtin_amdgcn_s_barrier();
  __builtin_amdgcn_sched_barrier(0);

  for (int t = 0; t < NT; ++t) {
    const int cur = t & 1;
    const char* Ap = reinterpret_cast<const char*>(&AsB[cur][0]);
    const char* Bp = reinterpret_cast<const char*>(&BsB[cur][0]);

    // A-half read: 8 x ds_read_b128 (mh selects 64-row half of wave's 128 rows)
    auto rdA = [&](int mh, short8* dst) {
#pragma unroll
      for (int mf = 0; mf < 4; ++mf)
#pragma unroll
        for (int ks = 0; ks < 2; ++ks) {
          const int row = wm * 128 + mh * 64 + mf * 16 + fr;
          const int byte = ((row * 64 + ks * 32 + fkE) * 2) ^ fxor;
          dst[mf * 2 + ks] = *reinterpret_cast<const short8*>(Ap + byte);
        }
    };
    // B-half read: 4 x ds_read_b128 (nh selects 32-col half of wave's 64 cols)
    auto rdB = [&](int nh, short8* dst) {
#pragma unroll
      for (int nf = 0; nf < 2; ++nf)
#pragma unroll
        for (int ks = 0; ks < 2; ++ks) {
          const int row = wn * 64 + nh * 32 + nf * 16 + fr;
          const int byte = ((row * 64 + ks * 32 + fkE) * 2) ^ fxor;
          dst[nf * 2 + ks] = *reinterpret_cast<const short8*>(Bp + byte);
        }
    };
    // one quadrant phase: 16 MFMA, setprio-wrapped, phase-pinned
    auto quad = [&](short8* a, short8* b, int mh, int nh) {
      __builtin_amdgcn_s_setprio(1);
#pragma unroll
      for (int mf = 0; mf < 4; ++mf)
#pragma unroll
        for (int nf = 0; nf < 2; ++nf)
#pragma unroll
          for (int ks = 0; ks < 2; ++ks)
            acc[mh * 4 + mf][nh * 2 + nf] = __builtin_amdgcn_mfma_f32_16x16x32_bf16(
                a[mf * 2 + ks], b[nf * 2 + ks], acc[mh * 4 + mf][nh * 2 + nf], 0, 0, 0);
      __builtin_amdgcn_s_setprio(0);
      __builtin_amdgcn_sched_barrier(0);
    };

    short8 aq0[8], aq1[8], bq0[4], bq1[4], bq0b[4];
    rdA(0, aq0);
    rdB(0, bq0);
    __builtin_amdgcn_sched_barrier(0);
    rdB(1, bq1);              // prefetch for phase 2
    quad(aq0, bq0, 0, 0);     // phase 1
    rdA(1, aq1);              // prefetch for phase 3
    quad(aq0, bq1, 0, 1);     // phase 2 (aq0 dies)
    rdB(0, bq0b);             // re-read B0 for phase 4 (caps reg peak)
    quad(aq1, bq1, 1, 1);     // phase 3 (bq1 dies)
    quad(aq1, bq0b, 1, 0);    // phase 4

    if (t + 1 < NT) {
      __builtin_amdgcn_s_barrier();            // all waves done reading buf[cur]
      if (t + 2 < NT) {
        STAGE(cur, t + 2);                     // refill freed buffer
        asm volatile("s_waitcnt vmcnt(8)" ::: "memory");   // tile t+1 landed
      } else {
        asm volatile("s_waitcnt vmcnt(0)" ::: "memory");   // final drain (once)
      }
      __builtin_amdgcn_sched_barrier(0);
      __builtin_amdgcn_s_barrier();            // buf[cur^1] visible to all waves
      __builtin_amdgcn_sched_barrier(0);
    }
  }
#undef STAGE

  // Epilogue. C/D layout: col = lane&15, row = (lane>>4)*4 + reg  [m89/m91]
  const long rowBase = (long)blockIdx.x * 256 + wm * 128 + ((lane >> 4) << 2);
  const int colBase = (int)blockIdx.y * 256 + wn * 64 + (lane & 15);
#pragma unroll
  for (int mf = 0; mf < 8; ++mf) {
#pragma unroll
    for (int nf = 0; nf < 4; ++nf) {
      const int col = colBase + nf * 16;
#pragma unroll
      for (int i = 0; i < 4; ++i) {
        const long r = rowBase + mf * 16 + i;
        float vv = acc[mf][nf][i];
        if constexpr (EPI == 0) {
          outB[r * (long)ldOut + col] = f2b(vv);
        } else if constexpr (EPI == 1) {
          oF[(long)zz * oBatch + r * (long)ldOut + col] = vv;
        } else if constexpr (EPI == 2) {
          float tt = vv + bias[col];
          float g = 0.5f * tt * (1.0f + erff(tt * 0.7071067811865476f));
          outB[r * (long)ldOut + col] = f2b(g);
        } else {
          const long idx = r * (long)ldOut + col;
          outF[idx] = vv + bias[col] + b2f(residB[idx]);
        }
      }
    }
  }
}

// ---------------------------------------------------------------------------
// Quadrant combine: y1 = attn + x, each output written exactly once.
// ---------------------------------------------------------------------------
__global__ __launch_bounds__(256) void combine_quadrants(
    const float* __restrict__ u, const float* __restrict__ v,
    const float* __restrict__ x, float* __restrict__ y) {
  const int k = blockIdx.x;            // 0..2048
  const int z = blockIdx.y;            // 0..7
  const long ub = ((long)z * 2304 + k) * 512;
  const long base = (long)z * 4096 * 768;
  const long rowA = base + (long)k * 768;
  const long rowB = base + (long)(4096 - k) * 768;
  const bool doRowB = (k != 0) && (k != 2048);
  for (int d = threadIdx.x; d <= 384; d += 256) {
    const float uu = u[ub + d];
    const float vv = v[ub + d];
    const float a1 = uu - vv;
    const float a2 = uu + vv;
    const int dd = 768 - d;
    const bool doColB = (d != 0) && (d != 384);
    y[rowA + d] = a1 + x[rowA + d];
    if (doColB) y[rowA + dd] = a2 + x[rowA + dd];
    if (doRowB) {
      y[rowB + d] = a2 + x[rowB + d];
      if (doColB) y[rowB + dd] = a1 + x[rowB + dd];
    }
  }
}

// ---------------------------------------------------------------------------
// Row LayerNorm over D=768. One 256-thread block per row, 3 elems/thread.
// ---------------------------------------------------------------------------
template <int MODE>
__global__ __launch_bounds__(256) void ln_row(
    const float* __restrict__ in, const float* __restrict__ gamma,
    const float* __restrict__ beta, unsigned short* __restrict__ outB,
    float* __restrict__ outF) {
  const long row = blockIdx.x;
  const float* p = in + row * 768;
  const int t = threadIdx.x;
  const float v0 = p[t], v1 = p[t + 256], v2 = p[t + 512];
  float s = v0 + v1 + v2;
  float q = v0 * v0 + v1 * v1 + v2 * v2;
#pragma unroll
  for (int off = 32; off > 0; off >>= 1) {
    s += __shfl_down(s, off, 64);
    q += __shfl_down(q, off, 64);
  }
  __shared__ float ss[4], sq[4];
  if ((t & 63) == 0) { ss[t >> 6] = s; sq[t >> 6] = q; }
  __syncthreads();
  const float S = ss[0] + ss[1] + ss[2] + ss[3];
  const float Q = sq[0] + sq[1] + sq[2] + sq[3];
  const float mu = S * (1.0f / 768.0f);
  const float var = Q * (1.0f / 768.0f) - mu * mu;
  const float rs = rsqrtf(var + 1e-6f);
  const float o0 = (v0 - mu) * rs * gamma[t] + beta[t];
  const float o1 = (v1 - mu) * rs * gamma[t + 256] + beta[t + 256];
  const float o2 = (v2 - mu) * rs * gamma[t + 512] + beta[t + 512];
  if constexpr (MODE == 0) {
    outB[row * 768 + t] = f2b(o0);
    outB[row * 768 + t + 256] = f2b(o1);
    outB[row * 768 + t + 512] = f2b(o2);
  } else {
    outF[row * 768 + t] = o0;
    outF[row * 768 + t + 256] = o1;
    outF[row * 768 + t + 512] = o2;
  }
}

// ---------------------------------------------------------------------------

extern "C" void kernel_launch(void* const* d_in, const int* in_sizes, int n_in,
                              void* d_out, int out_size, void* d_ws, size_t ws_size,
                              hipStream_t stream) {
  const float* x   = (const float*)d_in[0];   // (8,4096,768)
  const float* W1  = (const float*)d_in[1];   // (768,3072)
  const float* b1  = (const float*)d_in[2];   // (3072)
  const float* W2  = (const float*)d_in[3];   // (3072,768)
  const float* b2  = (const float*)d_in[4];   // (768)
  const float* g1  = (const float*)d_in[5];
  const float* be1 = (const float*)d_in[6];
  const float* g2  = (const float*)d_in[7];
  const float* be2 = (const float*)d_in[8];
  float* out = (float*)d_out;                 // fp32, also y1/y2 scratch

  char* ws = (char*)d_ws;
  unsigned short* xb   = (unsigned short*)(ws + 0L);           //  50,331,648
  unsigned short* Bt1  = (unsigned short*)(ws + 50331648L);    //   1,572,864
  unsigned short* Au   = (unsigned short*)(ws + 51904512L);    //  18,874,368
  unsigned short* Av   = (unsigned short*)(ws + 70778880L);    //  18,874,368
  unsigned short* T    = (unsigned short*)(ws + 89653248L);    //  67,108,864 -> ends 156,762,112
  unsigned short* BtUV = (unsigned short*)(ws + 156762112L);   //  67,108,864 -> ends 223,870,976
  float*          u    = (float*)        (ws + 0L);            //  37,748,736 (aliases xb; dead after GEMM1)
  float*          v    = (float*)        (ws + 89653248L);     //  37,748,736 (aliases T; dead after transpose_T)
  unsigned short* H    = (unsigned short*)(ws + 0L);           // 201,326,592 (aliases all FFT buffers, dead by GEMM3)
  unsigned short* o1b  = (unsigned short*)(ws + 201326592L);   //  50,331,648 (overlaps BtUV tail, dead by LN1)
  unsigned short* W1t  = (unsigned short*)(ws + 251658240L);   //   4,718,592
  unsigned short* W2t  = (unsigned short*)(ws + 256376832L);   //   4,718,592
  // total ws needed: 261,095,424 bytes (~249 MiB)

  // --- prep ---
  f32_to_bf16_vec<<<24576, 256, 0, stream>>>(x, xb);
  fill_bt1<<<3072, 256, 0, stream>>>(Bt1);
  fill_auv<<<36864, 256, 0, stream>>>(Au, Av);                 // 2304*4096/256
  transpose_f32_to_bf16<<<dim3(96, 24), 256, 0, stream>>>(W1, W1t, 768, 3072);
  transpose_f32_to_bf16<<<dim3(24, 96), 256, 0, stream>>>(W2, W2t, 3072, 768);

  // --- GEMM1: T = xb @ Bt1^T (row-major, ld 1024) ---
  gemm256<0><<<dim3(128, 4, 1), 512, 0, stream>>>(
      xb, Bt1, nullptr, nullptr, 768, 768, 768, 0L, 0L, 999,
      nullptr, nullptr, T, nullptr, nullptr, 1024);

  // --- transpose T -> BtU/BtV ([b][d][s]) ---
  transpose_T<<<dim3(128, 32, 8), 256, 0, stream>>>(T, BtUV);

  // --- GEMM_uv fused (z<8: u = C_S @ Tc; z>=8: v = S_S @ Ts) ---
  gemm256<1><<<dim3(9, 2, 16), 512, 0, stream>>>(
      Au, BtUV, Av, BtUV + 16777216L, 4096, 4096, 4096,
      512L * 4096L, 2304L * 512L, 8,
      u, v, nullptr, nullptr, nullptr, 512);

  // --- combine quadrants + x residual -> y1 (d_out) ---
  combine_quadrants<<<dim3(2049, 8), 256, 0, stream>>>(u, v, x, out);

  // --- LN1 -> out1 (bf16) ---
  ln_row<0><<<32768, 256, 0, stream>>>(out, g1, be1, o1b, nullptr);

  // --- GEMM3: H = gelu(out1 @ W1 + b1) ---
  gemm256<2><<<dim3(128, 12, 1), 512, 0, stream>>>(
      o1b, W1t, nullptr, nullptr, 768, 768, 768, 0L, 0L, 999,
      nullptr, nullptr, H, b1, nullptr, 3072);

  // --- GEMM4: y2 = H @ W2 + b2 + out1 -> d_out ---
  gemm256<3><<<dim3(128, 3, 1), 512, 0, stream>>>(
      H, W2t, nullptr, nullptr, 3072, 3072, 3072, 0L, 0L, 999,
      out, nullptr, nullptr, b2, o1b, 768);

  // --- LN2 in-place ---
  ln_row<1><<<32768, 256, 0, stream>>>(out, g2, be2, nullptr, out);
}

// Round 6
// 972.834 us; speedup vs baseline: 1.2541x; 1.2541x over previous
//
#include <hip/hip_runtime.h>
#include <cstdint>

// FNet block on MI355X.
//   attn = Re(FFT2(x)) via bf16 MFMA matmuls + real-input quadrant symmetry:
//     GEMM1: T[r][0:512]=Tc, T[r][512:1024]=Ts   (M=32768, N=1024, K=768)
//     transpose_T: BtU[b][d][s]=Tc[s,d], BtV[b][d][s]=Ts[s,d]
//     GEMM_uv (fused, z=0..15): u (cos) / v (sin), M=2304(pad), N=512, K=4096
//     combine: attn[k,d]=u-v; [k,768-d]=u+v; [4096-k,d]=u+v; [4096-k,768-d]=u-v
//   LN1 -> out1 (bf16)
//   GEMM3: H = gelu(out1 @ W1 + b1)       (M=32768, N=3072, K=768)
//   GEMM4: y2 = H @ W2 + b2 + out1        (M=32768, N=768, K=3072)
//   LN2 in-place on d_out.
//
// GEMM core (round 6): true m201-style fine interleave. 256x256 tile, BK=64,
// 8 waves. LDS = 2 buf x 2 half-slots x (A,B), half-slot = 16 KB, 128 KiB total.
// Half-slots are partitioned BY READ PHASE:
//   A-slot h = rows {wm*128 + h*64 + 0..63}  (read only in phase 1 (h=0) / 3 (h=1))
//   B-slot h = rows {wn*64 + h*32 + 0..31}   (read only in phase 1 (h=0) / 2 (h=1))
// Per K-tile: 4 phases, each {ds_read frags ; stage ONE half-slot ; barrier ;
// lgkmcnt(0) ; setprio(1) 16 MFMA setprio(0) ; barrier}. Stage targets always
// have last-read >= 1 barrier earlier (race-free). Tile boundary: vmcnt(6)
// (3 half-slots = 6 loads in flight; never 0 in main loop) + barrier.

typedef __attribute__((ext_vector_type(8))) short short8;
typedef __attribute__((ext_vector_type(4))) float f32x4;

__device__ __forceinline__ unsigned short f2b(float f) {
  union { float f; uint32_t u; } c; c.f = f;
  uint32_t u = c.u;
  u += 0x7FFFu + ((u >> 16) & 1u);   // round-to-nearest-even
  return (unsigned short)(u >> 16);
}
__device__ __forceinline__ float b2f(unsigned short h) {
  union { uint32_t u; float f; } c; c.u = ((uint32_t)h) << 16;
  return c.f;
}

// ---------------------------------------------------------------------------
// Fill / convert kernels (unchanged, verified)
// ---------------------------------------------------------------------------

__global__ __launch_bounds__(256) void f32_to_bf16_vec(
    const float* __restrict__ in, unsigned short* __restrict__ out) {
  long i = (long)blockIdx.x * 256 + threadIdx.x;   // element-of-4 index
  float4 v = reinterpret_cast<const float4*>(in)[i];
  ushort4 o;
  o.x = f2b(v.x); o.y = f2b(v.y); o.z = f2b(v.z); o.w = f2b(v.w);
  reinterpret_cast<ushort4*>(out)[i] = o;
}

// Bt1: (1024 x 768). Row j<512: cos(2*pi*j*n/768); row j>=512: sin(2*pi*(j-512)*n/768).
__global__ __launch_bounds__(256) void fill_bt1(unsigned short* __restrict__ Bt1) {
  int i = blockIdx.x * 256 + threadIdx.x;          // < 1024*768
  int j = i / 768;
  int n = i - j * 768;
  int jj = j & 511;
  int m = (jj * n) % 768;
  float ang = (float)m * (6.283185307179586f / 768.0f);
  Bt1[i] = f2b((j < 512) ? cosf(ang) : sinf(ang));
}

// Au[k][s] = cos(2*pi*k*s/4096), Av[k][s] = sin(...), k=0..2303 (padded), s=0..4095.
__global__ __launch_bounds__(256) void fill_auv(
    unsigned short* __restrict__ Au, unsigned short* __restrict__ Av) {
  long i = (long)blockIdx.x * 256 + threadIdx.x;   // < 2304*4096
  int k = (int)(i >> 12);
  int s = (int)(i & 4095);
  int mm = (k * s) & 4095;
  float ang = (float)mm * (6.283185307179586f / 4096.0f);
  Au[i] = f2b(cosf(ang));
  Av[i] = f2b(sinf(ang));
}

// out[c][r] = bf16(in[r][c]); R,C multiples of 32  (for W1, W2)
__global__ __launch_bounds__(256) void transpose_f32_to_bf16(
    const float* __restrict__ in, unsigned short* __restrict__ out, int R, int C) {
  __shared__ float tile[32][33];
  const int c0 = blockIdx.x * 32;
  const int r0 = blockIdx.y * 32;
  const int tx = threadIdx.x & 31;
  const int ty = threadIdx.x >> 5;   // 0..7
#pragma unroll
  for (int i = ty; i < 32; i += 8)
    tile[i][tx] = in[(long)(r0 + i) * C + c0 + tx];
  __syncthreads();
#pragma unroll
  for (int i = ty; i < 32; i += 8)
    out[(long)(c0 + i) * R + r0 + tx] = f2b(tile[tx][i]);
}

// BtUV[(d<512?0:HALF) + (b*512 + (d&511))*4096 + s] = T[(b*4096+s)*1024 + d]
__global__ __launch_bounds__(256) void transpose_T(
    const unsigned short* __restrict__ T, unsigned short* __restrict__ BtUV) {
  __shared__ unsigned short tile[32][33];
  const int s0 = blockIdx.x * 32;
  const int d0 = blockIdx.y * 32;
  const int b  = blockIdx.z;
  const int tx = threadIdx.x & 31;
  const int ty = threadIdx.x >> 5;   // 0..7
  const unsigned short* Tb = T + ((long)b * 4096 + s0) * 1024 + d0;
#pragma unroll
  for (int i = ty; i < 32; i += 8)
    tile[i][tx] = Tb[(long)i * 1024 + tx];       // tile[s_local][d_local]
  __syncthreads();
#pragma unroll
  for (int i = ty; i < 32; i += 8) {
    const int d = d0 + i;
    const long off = (d < 512) ? 0L : 16777216L;
    BtUV[off + ((long)b * 512 + (d & 511)) * 4096 + s0 + tx] = tile[tx][i];
  }
}

// ---------------------------------------------------------------------------
// GEMM256 with phase-interleaved pipeline (see header comment).
// Epilogues: 0 = bf16 store (GEMM1->T); 1 = fp32 z-batched store, z>=zSplit
//            switches to (A2p,Bt2p,outF2) operand set (fused GEMM_u/GEMM_v);
//            2 = +bias, exact gelu, bf16 (GEMM3->H); 3 = +bias+bf16resid, fp32.
// M,N multiples of 256; K multiple of 64; K/64 >= 4.
// ---------------------------------------------------------------------------

template <int EPI>
__global__ __launch_bounds__(512, 2) void gemm256(
    const unsigned short* __restrict__ A, const unsigned short* __restrict__ Bt,
    const unsigned short* __restrict__ A2p, const unsigned short* __restrict__ Bt2p,
    int K, int lda, int ldb, long bBatch, long oBatch, int zSplit,
    float* __restrict__ outF, float* __restrict__ outF2,
    unsigned short* __restrict__ outB,
    const float* __restrict__ bias, const unsigned short* __restrict__ residB,
    int ldOut) {
  __shared__ __align__(16) unsigned short As[2][2][8192];   // [buf][slot][16KB]
  __shared__ __align__(16) unsigned short Bs[2][2][8192];

  const int tid = threadIdx.x;
  const int lane = tid & 63;
  const int wid = tid >> 6;          // 0..7
  const int wm = wid >> 2;           // 0..1
  const int wn = wid & 3;            // 0..3

  int zz = blockIdx.z;
  const unsigned short* Ax = A;
  const unsigned short* Bx = Bt;
  float* oF = outF;
  if (EPI == 1 && zz >= zSplit) { Ax = A2p; Bx = Bt2p; oF = outF2; zz -= zSplit; }

  const unsigned short* Ab = Ax + (long)blockIdx.x * 256 * lda;
  const unsigned short* Bb = Bx + (long)zz * bBatch + (long)blockIdx.y * 256 * ldb;

  const int NT = K >> 6;             // #K-tiles (>= 12 for all our shapes)

  // Staging lane pattern (identical to verified round-4/5 kernel):
  // linear LDS dest, T2 swizzle pre-applied to the per-lane GLOBAL column.
  const int srow = lane >> 3;                      // row within 8-row region
  const int scolE = ((lane & 7) ^ srow) << 3;      // pre-swizzled col (elems)

  // A-slot h: virtual row vr = wm*64 + rr  ->  global row wm*128 + h*64 + rr
#define STGA(dst, kt, h) do {                                                          \
    _Pragma("unroll")                                                                  \
    for (int i_ = 0; i_ < 2; ++i_) {                                                   \
      const int reg_ = i_ * 8 + wid;                                                   \
      const int vr_ = reg_ * 8 + srow;                                                 \
      const int grow_ = ((vr_ >> 6) << 7) + (h) * 64 + (vr_ & 63);                     \
      __builtin_amdgcn_global_load_lds(                                                \
        (const __attribute__((address_space(1))) void*)(Ab + (long)grow_ * lda + (long)(kt) * 64 + scolE), \
        (__attribute__((address_space(3))) void*)((dst) + reg_ * 512), 16, 0, 0);      \
    } } while (0)
  // B-slot h: virtual row vr = wn*32 + rr  ->  global row wn*64 + h*32 + rr
#define STGB(dst, kt, h) do {                                                          \
    _Pragma("unroll")                                                                  \
    for (int i_ = 0; i_ < 2; ++i_) {                                                   \
      const int reg_ = i_ * 8 + wid;                                                   \
      const int vr_ = reg_ * 8 + srow;                                                 \
      const int grow_ = ((vr_ >> 5) << 6) + (h) * 32 + (vr_ & 31);                     \
      __builtin_amdgcn_global_load_lds(                                                \
        (const __attribute__((address_space(1))) void*)(Bb + (long)grow_ * ldb + (long)(kt) * 64 + scolE), \
        (__attribute__((address_space(3))) void*)((dst) + reg_ * 512), 16, 0, 0);      \
    } } while (0)

  const int fr = lane & 15;          // frag row within 16
  const int fkE = (lane >> 4) << 3;  // k-offset elems (0,8,16,24)
  const int fxor = (lane & 7) << 4;  // T2 swizzle XOR (lane-constant)

  f32x4 acc[8][4] = {};

  // prologue: tile0 all 4 slots + tile1 {A0, A1, B0} = 7 stages (14 loads)
  STGA(&As[0][0][0], 0, 0);
  STGA(&As[0][1][0], 0, 1);
  STGB(&Bs[0][0][0], 0, 0);
  STGB(&Bs[0][1][0], 0, 1);
  STGA(&As[1][0][0], 1, 0);
  STGA(&As[1][1][0], 1, 1);
  STGB(&Bs[1][0][0], 1, 0);

  for (int t = 0; t < NT; ++t) {
    const int c = t & 1;

    // ---- tile boundary: tile t's 4 slots landed; 3 newest stages in flight ----
    if (t + 1 < NT) { asm volatile("s_waitcnt vmcnt(6)" ::: "memory"); }
    else            { asm volatile("s_waitcnt vmcnt(0)" ::: "memory"); }
    __builtin_amdgcn_sched_barrier(0);
    __builtin_amdgcn_s_barrier();
    __builtin_amdgcn_sched_barrier(0);

    const char* A0p = (const char*)&As[c][0][0];
    const char* A1p = (const char*)&As[c][1][0];
    const char* B0p = (const char*)&Bs[c][0][0];
    const char* B1p = (const char*)&Bs[c][1][0];

    short8 aq0[8], aq1[8], bq0[4], bq1[4];

    auto rdA = [&](const char* p, short8* dst) {
#pragma unroll
      for (int mf = 0; mf < 4; ++mf)
#pragma unroll
        for (int ks = 0; ks < 2; ++ks) {
          const int vr = wm * 64 + mf * 16 + fr;
          const int byte = ((vr * 64 + ks * 32 + fkE) * 2) ^ fxor;
          dst[mf * 2 + ks] = *reinterpret_cast<const short8*>(p + byte);
        }
    };
    auto rdB = [&](const char* p, short8* dst) {
#pragma unroll
      for (int nf = 0; nf < 2; ++nf)
#pragma unroll
        for (int ks = 0; ks < 2; ++ks) {
          const int vr = wn * 32 + nf * 16 + fr;
          const int byte = ((vr * 64 + ks * 32 + fkE) * 2) ^ fxor;
          dst[nf * 2 + ks] = *reinterpret_cast<const short8*>(p + byte);
        }
    };
    auto quad = [&](short8* a, short8* b, int mh, int nh) {
      __builtin_amdgcn_s_setprio(1);
#pragma unroll
      for (int mf = 0; mf < 4; ++mf)
#pragma unroll
        for (int nf = 0; nf < 2; ++nf)
#pragma unroll
          for (int ks = 0; ks < 2; ++ks)
            acc[mh * 4 + mf][nh * 2 + nf] = __builtin_amdgcn_mfma_f32_16x16x32_bf16(
                a[mf * 2 + ks], b[nf * 2 + ks], acc[mh * 4 + mf][nh * 2 + nf], 0, 0, 0);
      __builtin_amdgcn_s_setprio(0);
    };

    // ---- P1: read aq0,bq0 (slots A0,B0) ; stage B1(t+1) -> buf c^1 ----
    rdA(A0p, aq0);
    rdB(B0p, bq0);
    if (t + 1 < NT) STGB(&Bs[c ^ 1][1][0], t + 1, 1);
    __builtin_amdgcn_sched_barrier(0);
    __builtin_amdgcn_s_barrier();
    asm volatile("s_waitcnt lgkmcnt(0)" ::: "memory");
    __builtin_amdgcn_sched_barrier(0);
    quad(aq0, bq0, 0, 0);
    __builtin_amdgcn_sched_barrier(0);
    __builtin_amdgcn_s_barrier();
    __builtin_amdgcn_sched_barrier(0);

    // ---- P2: read bq1 (slot B1) ; stage A0(t+2) -> buf c (A0 last read P1) ----
    rdB(B1p, bq1);
    if (t + 2 < NT) STGA(&As[c][0][0], t + 2, 0);
    __builtin_amdgcn_sched_barrier(0);
    __builtin_amdgcn_s_barrier();
    asm volatile("s_waitcnt lgkmcnt(0)" ::: "memory");
    __builtin_amdgcn_sched_barrier(0);
    quad(aq0, bq1, 0, 1);
    __builtin_amdgcn_sched_barrier(0);
    __builtin_amdgcn_s_barrier();
    __builtin_amdgcn_sched_barrier(0);

    // ---- P3: read aq1 (slot A1) ; stage B0(t+2) -> buf c (B0 last read P1) ----
    rdA(A1p, aq1);
    if (t + 2 < NT) STGB(&Bs[c][0][0], t + 2, 0);
    __builtin_amdgcn_sched_barrier(0);
    __builtin_amdgcn_s_barrier();
    asm volatile("s_waitcnt lgkmcnt(0)" ::: "memory");
    __builtin_amdgcn_sched_barrier(0);
    quad(aq1, bq1, 1, 1);
    __builtin_amdgcn_sched_barrier(0);
    __builtin_amdgcn_s_barrier();
    __builtin_amdgcn_sched_barrier(0);

    // ---- P4: stage A1(t+2) -> buf c (A1 last read P3) ; no new reads ----
    if (t + 2 < NT) STGA(&As[c][1][0], t + 2, 1);
    __builtin_amdgcn_sched_barrier(0);
    __builtin_amdgcn_s_barrier();
    __builtin_amdgcn_sched_barrier(0);
    quad(aq1, bq0, 1, 0);
    // loop-top boundary barrier follows
  }
#undef STGA
#undef STGB

  // Epilogue. C/D layout: col = lane&15, row = (lane>>4)*4 + reg  [m89/m91]
  const long rowBase = (long)blockIdx.x * 256 + wm * 128 + ((lane >> 4) << 2);
  const int colBase = (int)blockIdx.y * 256 + wn * 64 + (lane & 15);
#pragma unroll
  for (int mf = 0; mf < 8; ++mf) {
#pragma unroll
    for (int nf = 0; nf < 4; ++nf) {
      const int col = colBase + nf * 16;
#pragma unroll
      for (int i = 0; i < 4; ++i) {
        const long r = rowBase + mf * 16 + i;
        float vv = acc[mf][nf][i];
        if constexpr (EPI == 0) {
          outB[r * (long)ldOut + col] = f2b(vv);
        } else if constexpr (EPI == 1) {
          oF[(long)zz * oBatch + r * (long)ldOut + col] = vv;
        } else if constexpr (EPI == 2) {
          float tt = vv + bias[col];
          float g = 0.5f * tt * (1.0f + erff(tt * 0.7071067811865476f));
          outB[r * (long)ldOut + col] = f2b(g);
        } else {
          const long idx = r * (long)ldOut + col;
          outF[idx] = vv + bias[col] + b2f(residB[idx]);
        }
      }
    }
  }
}

// ---------------------------------------------------------------------------
// Quadrant combine: y1 = attn + x, each output written exactly once.
// ---------------------------------------------------------------------------
__global__ __launch_bounds__(256) void combine_quadrants(
    const float* __restrict__ u, const float* __restrict__ v,
    const float* __restrict__ x, float* __restrict__ y) {
  const int k = blockIdx.x;            // 0..2048
  const int z = blockIdx.y;            // 0..7
  const long ub = ((long)z * 2304 + k) * 512;
  const long base = (long)z * 4096 * 768;
  const long rowA = base + (long)k * 768;
  const long rowB = base + (long)(4096 - k) * 768;
  const bool doRowB = (k != 0) && (k != 2048);
  for (int d = threadIdx.x; d <= 384; d += 256) {
    const float uu = u[ub + d];
    const float vv = v[ub + d];
    const float a1 = uu - vv;
    const float a2 = uu + vv;
    const int dd = 768 - d;
    const bool doColB = (d != 0) && (d != 384);
    y[rowA + d] = a1 + x[rowA + d];
    if (doColB) y[rowA + dd] = a2 + x[rowA + dd];
    if (doRowB) {
      y[rowB + d] = a2 + x[rowB + d];
      if (doColB) y[rowB + dd] = a1 + x[rowB + dd];
    }
  }
}

// ---------------------------------------------------------------------------
// Row LayerNorm over D=768. One 256-thread block per row, 3 elems/thread.
// ---------------------------------------------------------------------------
template <int MODE>
__global__ __launch_bounds__(256) void ln_row(
    const float* __restrict__ in, const float* __restrict__ gamma,
    const float* __restrict__ beta, unsigned short* __restrict__ outB,
    float* __restrict__ outF) {
  const long row = blockIdx.x;
  const float* p = in + row * 768;
  const int t = threadIdx.x;
  const float v0 = p[t], v1 = p[t + 256], v2 = p[t + 512];
  float s = v0 + v1 + v2;
  float q = v0 * v0 + v1 * v1 + v2 * v2;
#pragma unroll
  for (int off = 32; off > 0; off >>= 1) {
    s += __shfl_down(s, off, 64);
    q += __shfl_down(q, off, 64);
  }
  __shared__ float ss[4], sq[4];
  if ((t & 63) == 0) { ss[t >> 6] = s; sq[t >> 6] = q; }
  __syncthreads();
  const float S = ss[0] + ss[1] + ss[2] + ss[3];
  const float Q = sq[0] + sq[1] + sq[2] + sq[3];
  const float mu = S * (1.0f / 768.0f);
  const float var = Q * (1.0f / 768.0f) - mu * mu;
  const float rs = rsqrtf(var + 1e-6f);
  const float o0 = (v0 - mu) * rs * gamma[t] + beta[t];
  const float o1 = (v1 - mu) * rs * gamma[t + 256] + beta[t + 256];
  const float o2 = (v2 - mu) * rs * gamma[t + 512] + beta[t + 512];
  if constexpr (MODE == 0) {
    outB[row * 768 + t] = f2b(o0);
    outB[row * 768 + t + 256] = f2b(o1);
    outB[row * 768 + t + 512] = f2b(o2);
  } else {
    outF[row * 768 + t] = o0;
    outF[row * 768 + t + 256] = o1;
    outF[row * 768 + t + 512] = o2;
  }
}

// ---------------------------------------------------------------------------

extern "C" void kernel_launch(void* const* d_in, const int* in_sizes, int n_in,
                              void* d_out, int out_size, void* d_ws, size_t ws_size,
                              hipStream_t stream) {
  const float* x   = (const float*)d_in[0];   // (8,4096,768)
  const float* W1  = (const float*)d_in[1];   // (768,3072)
  const float* b1  = (const float*)d_in[2];   // (3072)
  const float* W2  = (const float*)d_in[3];   // (3072,768)
  const float* b2  = (const float*)d_in[4];   // (768)
  const float* g1  = (const float*)d_in[5];
  const float* be1 = (const float*)d_in[6];
  const float* g2  = (const float*)d_in[7];
  const float* be2 = (const float*)d_in[8];
  float* out = (float*)d_out;                 // fp32, also y1/y2 scratch

  char* ws = (char*)d_ws;
  unsigned short* xb   = (unsigned short*)(ws + 0L);           //  50,331,648
  unsigned short* Bt1  = (unsigned short*)(ws + 50331648L);    //   1,572,864
  unsigned short* Au   = (unsigned short*)(ws + 51904512L);    //  18,874,368
  unsigned short* Av   = (unsigned short*)(ws + 70778880L);    //  18,874,368
  unsigned short* T    = (unsigned short*)(ws + 89653248L);    //  67,108,864 -> ends 156,762,112
  unsigned short* BtUV = (unsigned short*)(ws + 156762112L);   //  67,108,864 -> ends 223,870,976
  float*          u    = (float*)        (ws + 0L);            //  37,748,736 (aliases xb; dead after GEMM1)
  float*          v    = (float*)        (ws + 89653248L);     //  37,748,736 (aliases T; dead after transpose_T)
  unsigned short* H    = (unsigned short*)(ws + 0L);           // 201,326,592 (aliases all FFT buffers, dead by GEMM3)
  unsigned short* o1b  = (unsigned short*)(ws + 201326592L);   //  50,331,648 (overlaps BtUV tail, dead by LN1)
  unsigned short* W1t  = (unsigned short*)(ws + 251658240L);   //   4,718,592
  unsigned short* W2t  = (unsigned short*)(ws + 256376832L);   //   4,718,592
  // total ws needed: 261,095,424 bytes (~249 MiB)

  // --- prep ---
  f32_to_bf16_vec<<<24576, 256, 0, stream>>>(x, xb);
  fill_bt1<<<3072, 256, 0, stream>>>(Bt1);
  fill_auv<<<36864, 256, 0, stream>>>(Au, Av);                 // 2304*4096/256
  transpose_f32_to_bf16<<<dim3(96, 24), 256, 0, stream>>>(W1, W1t, 768, 3072);
  transpose_f32_to_bf16<<<dim3(24, 96), 256, 0, stream>>>(W2, W2t, 3072, 768);

  // --- GEMM1: T = xb @ Bt1^T (row-major, ld 1024) ---
  gemm256<0><<<dim3(128, 4, 1), 512, 0, stream>>>(
      xb, Bt1, nullptr, nullptr, 768, 768, 768, 0L, 0L, 999,
      nullptr, nullptr, T, nullptr, nullptr, 1024);

  // --- transpose T -> BtU/BtV ([b][d][s]) ---
  transpose_T<<<dim3(128, 32, 8), 256, 0, stream>>>(T, BtUV);

  // --- GEMM_uv fused (z<8: u = C_S @ Tc; z>=8: v = S_S @ Ts) ---
  gemm256<1><<<dim3(9, 2, 16), 512, 0, stream>>>(
      Au, BtUV, Av, BtUV + 16777216L, 4096, 4096, 4096,
      512L * 4096L, 2304L * 512L, 8,
      u, v, nullptr, nullptr, nullptr, 512);

  // --- combine quadrants + x residual -> y1 (d_out) ---
  combine_quadrants<<<dim3(2049, 8), 256, 0, stream>>>(u, v, x, out);

  // --- LN1 -> out1 (bf16) ---
  ln_row<0><<<32768, 256, 0, stream>>>(out, g1, be1, o1b, nullptr);

  // --- GEMM3: H = gelu(out1 @ W1 + b1) ---
  gemm256<2><<<dim3(128, 12, 1), 512, 0, stream>>>(
      o1b, W1t, nullptr, nullptr, 768, 768, 768, 0L, 0L, 999,
      nullptr, nullptr, H, b1, nullptr, 3072);

  // --- GEMM4: y2 = H @ W2 + b2 + out1 -> d_out ---
  gemm256<3><<<dim3(128, 3, 1), 512, 0, stream>>>(
      H, W2t, nullptr, nullptr, 3072, 3072, 3072, 0L, 0L, 999,
      out, nullptr, nullptr, b2, o1b, 768);

  // --- LN2 in-place ---
  ln_row<1><<<32768, 256, 0, stream>>>(out, g2, be2, nullptr, out);
}

// Round 7
// 876.173 us; speedup vs baseline: 1.3925x; 1.1103x over previous
//
#include <hip/hip_runtime.h>
#include <cstdint>

// FNet block on MI355X.
//   attn = Re(FFT2(x)) via bf16 MFMA matmuls + real-input quadrant symmetry:
//     GEMM1: T[r][0:512]=Tc, T[r][512:1024]=Ts   (M=32768, N=1024, K=768)
//     transpose_T: BtU[b][d][s]=Tc[s,d], BtV[b][d][s]=Ts[s,d]
//     GEMM_uv (fused, z=0..15): u (cos) / v (sin), M=2304(pad), N=512, K=4096
//     combine_ln: quadrant-combine u+-v, +x residual, FUSED row-LayerNorm,
//                 writes out1 bf16 directly (y1 never materialized)
//   GEMM3: H = gelu(out1 @ W1 + b1)       (M=32768, N=3072, K=768)  [fast tanh-gelu]
//   GEMM4: y2 = H @ W2 + b2 + out1        (M=32768, N=768, K=3072)
//   LN2 in-place on d_out.
//
// GEMM core (unchanged from round 6, verified): 256x256 tile, BK=64, 8 waves,
// LDS 2 buf x 2 half-slots x (A,B) = 128 KiB, phase-interleaved 4-phase/K-tile
// schedule, counted vmcnt(6), T2 swizzle, setprio around MFMA clusters.

typedef __attribute__((ext_vector_type(8))) short short8;
typedef __attribute__((ext_vector_type(4))) float f32x4;

__device__ __forceinline__ unsigned short f2b(float f) {
  union { float f; uint32_t u; } c; c.f = f;
  uint32_t u = c.u;
  u += 0x7FFFu + ((u >> 16) & 1u);   // round-to-nearest-even
  return (unsigned short)(u >> 16);
}
__device__ __forceinline__ float b2f(unsigned short h) {
  union { uint32_t u; float f; } c; c.u = ((uint32_t)h) << 16;
  return c.f;
}

// fast GELU (tanh form), ~9 VALU: g = x*E/(E+1), E = exp(2*inner),
// inner = 0.79788456*x*(1 + 0.044715*x^2). max |err vs exact erf-gelu| ~3e-3.
__device__ __forceinline__ float gelu_fast(float x) {
  float x2 = x * x;
  float inner = x * fmaf(x2, 0.0356774081f, 0.7978845608f);
  float zz = fminf(inner * 2.885390082f, 80.0f);   // exp2 arg = 2*inner*log2(e)
  float E, r;
  asm("v_exp_f32 %0, %1" : "=v"(E) : "v"(zz));
  float den = E + 1.0f;
  asm("v_rcp_f32 %0, %1" : "=v"(r) : "v"(den));
  return x * E * r;
}

// ---------------------------------------------------------------------------
// Fill / convert kernels (unchanged, verified)
// ---------------------------------------------------------------------------

__global__ __launch_bounds__(256) void f32_to_bf16_vec(
    const float* __restrict__ in, unsigned short* __restrict__ out) {
  long i = (long)blockIdx.x * 256 + threadIdx.x;   // element-of-4 index
  float4 v = reinterpret_cast<const float4*>(in)[i];
  ushort4 o;
  o.x = f2b(v.x); o.y = f2b(v.y); o.z = f2b(v.z); o.w = f2b(v.w);
  reinterpret_cast<ushort4*>(out)[i] = o;
}

// Bt1: (1024 x 768). Row j<512: cos(2*pi*j*n/768); row j>=512: sin(2*pi*(j-512)*n/768).
__global__ __launch_bounds__(256) void fill_bt1(unsigned short* __restrict__ Bt1) {
  int i = blockIdx.x * 256 + threadIdx.x;          // < 1024*768
  int j = i / 768;
  int n = i - j * 768;
  int jj = j & 511;
  int m = (jj * n) % 768;
  float ang = (float)m * (6.283185307179586f / 768.0f);
  Bt1[i] = f2b((j < 512) ? cosf(ang) : sinf(ang));
}

// Au[k][s] = cos(2*pi*k*s/4096), Av[k][s] = sin(...), k=0..2303 (padded), s=0..4095.
__global__ __launch_bounds__(256) void fill_auv(
    unsigned short* __restrict__ Au, unsigned short* __restrict__ Av) {
  long i = (long)blockIdx.x * 256 + threadIdx.x;   // < 2304*4096
  int k = (int)(i >> 12);
  int s = (int)(i & 4095);
  int mm = (k * s) & 4095;
  float ang = (float)mm * (6.283185307179586f / 4096.0f);
  Au[i] = f2b(cosf(ang));
  Av[i] = f2b(sinf(ang));
}

// out[c][r] = bf16(in[r][c]); R,C multiples of 32  (for W1, W2)
__global__ __launch_bounds__(256) void transpose_f32_to_bf16(
    const float* __restrict__ in, unsigned short* __restrict__ out, int R, int C) {
  __shared__ float tile[32][33];
  const int c0 = blockIdx.x * 32;
  const int r0 = blockIdx.y * 32;
  const int tx = threadIdx.x & 31;
  const int ty = threadIdx.x >> 5;   // 0..7
#pragma unroll
  for (int i = ty; i < 32; i += 8)
    tile[i][tx] = in[(long)(r0 + i) * C + c0 + tx];
  __syncthreads();
#pragma unroll
  for (int i = ty; i < 32; i += 8)
    out[(long)(c0 + i) * R + r0 + tx] = f2b(tile[tx][i]);
}

// BtUV[(d<512?0:HALF) + (b*512 + (d&511))*4096 + s] = T[(b*4096+s)*1024 + d]
__global__ __launch_bounds__(256) void transpose_T(
    const unsigned short* __restrict__ T, unsigned short* __restrict__ BtUV) {
  __shared__ unsigned short tile[32][33];
  const int s0 = blockIdx.x * 32;
  const int d0 = blockIdx.y * 32;
  const int b  = blockIdx.z;
  const int tx = threadIdx.x & 31;
  const int ty = threadIdx.x >> 5;   // 0..7
  const unsigned short* Tb = T + ((long)b * 4096 + s0) * 1024 + d0;
#pragma unroll
  for (int i = ty; i < 32; i += 8)
    tile[i][tx] = Tb[(long)i * 1024 + tx];       // tile[s_local][d_local]
  __syncthreads();
#pragma unroll
  for (int i = ty; i < 32; i += 8) {
    const int d = d0 + i;
    const long off = (d < 512) ? 0L : 16777216L;
    BtUV[off + ((long)b * 512 + (d & 511)) * 4096 + s0 + tx] = tile[tx][i];
  }
}

// ---------------------------------------------------------------------------
// GEMM256 with phase-interleaved pipeline (unchanged from round 6).
// Epilogues: 0 = bf16 store (GEMM1->T); 1 = fp32 z-batched store, z>=zSplit
//            switches to (A2p,Bt2p,outF2) operand set (fused GEMM_u/GEMM_v);
//            2 = +bias, fast gelu, bf16 (GEMM3->H); 3 = +bias+bf16resid, fp32.
// M,N multiples of 256; K multiple of 64; K/64 >= 4.
// ---------------------------------------------------------------------------

template <int EPI>
__global__ __launch_bounds__(512, 2) void gemm256(
    const unsigned short* __restrict__ A, const unsigned short* __restrict__ Bt,
    const unsigned short* __restrict__ A2p, const unsigned short* __restrict__ Bt2p,
    int K, int lda, int ldb, long bBatch, long oBatch, int zSplit,
    float* __restrict__ outF, float* __restrict__ outF2,
    unsigned short* __restrict__ outB,
    const float* __restrict__ bias, const unsigned short* __restrict__ residB,
    int ldOut) {
  __shared__ __align__(16) unsigned short As[2][2][8192];   // [buf][slot][16KB]
  __shared__ __align__(16) unsigned short Bs[2][2][8192];

  const int tid = threadIdx.x;
  const int lane = tid & 63;
  const int wid = tid >> 6;          // 0..7
  const int wm = wid >> 2;           // 0..1
  const int wn = wid & 3;            // 0..3

  int zz = blockIdx.z;
  const unsigned short* Ax = A;
  const unsigned short* Bx = Bt;
  float* oF = outF;
  if (EPI == 1 && zz >= zSplit) { Ax = A2p; Bx = Bt2p; oF = outF2; zz -= zSplit; }

  const unsigned short* Ab = Ax + (long)blockIdx.x * 256 * lda;
  const unsigned short* Bb = Bx + (long)zz * bBatch + (long)blockIdx.y * 256 * ldb;

  const int NT = K >> 6;             // #K-tiles (>= 12 for all our shapes)

  // Staging: linear LDS dest, T2 swizzle pre-applied to per-lane GLOBAL column.
  const int srow = lane >> 3;                      // row within 8-row region
  const int scolE = ((lane & 7) ^ srow) << 3;      // pre-swizzled col (elems)

  // A-slot h: virtual row vr = wm*64 + rr  ->  global row wm*128 + h*64 + rr
#define STGA(dst, kt, h) do {                                                          \
    _Pragma("unroll")                                                                  \
    for (int i_ = 0; i_ < 2; ++i_) {                                                   \
      const int reg_ = i_ * 8 + wid;                                                   \
      const int vr_ = reg_ * 8 + srow;                                                 \
      const int grow_ = ((vr_ >> 6) << 7) + (h) * 64 + (vr_ & 63);                     \
      __builtin_amdgcn_global_load_lds(                                                \
        (const __attribute__((address_space(1))) void*)(Ab + (long)grow_ * lda + (long)(kt) * 64 + scolE), \
        (__attribute__((address_space(3))) void*)((dst) + reg_ * 512), 16, 0, 0);      \
    } } while (0)
  // B-slot h: virtual row vr = wn*32 + rr  ->  global row wn*64 + h*32 + rr
#define STGB(dst, kt, h) do {                                                          \
    _Pragma("unroll")                                                                  \
    for (int i_ = 0; i_ < 2; ++i_) {                                                   \
      const int reg_ = i_ * 8 + wid;                                                   \
      const int vr_ = reg_ * 8 + srow;                                                 \
      const int grow_ = ((vr_ >> 5) << 6) + (h) * 32 + (vr_ & 31);                     \
      __builtin_amdgcn_global_load_lds(                                                \
        (const __attribute__((address_space(1))) void*)(Bb + (long)grow_ * ldb + (long)(kt) * 64 + scolE), \
        (__attribute__((address_space(3))) void*)((dst) + reg_ * 512), 16, 0, 0);      \
    } } while (0)

  const int fr = lane & 15;          // frag row within 16
  const int fkE = (lane >> 4) << 3;  // k-offset elems (0,8,16,24)
  const int fxor = (lane & 7) << 4;  // T2 swizzle XOR (lane-constant)

  f32x4 acc[8][4] = {};

  // prologue: tile0 all 4 slots + tile1 {A0, A1, B0} = 7 stages (14 loads)
  STGA(&As[0][0][0], 0, 0);
  STGA(&As[0][1][0], 0, 1);
  STGB(&Bs[0][0][0], 0, 0);
  STGB(&Bs[0][1][0], 0, 1);
  STGA(&As[1][0][0], 1, 0);
  STGA(&As[1][1][0], 1, 1);
  STGB(&Bs[1][0][0], 1, 0);

  for (int t = 0; t < NT; ++t) {
    const int c = t & 1;

    // ---- tile boundary: tile t's 4 slots landed; 3 newest stages in flight ----
    if (t + 1 < NT) { asm volatile("s_waitcnt vmcnt(6)" ::: "memory"); }
    else            { asm volatile("s_waitcnt vmcnt(0)" ::: "memory"); }
    __builtin_amdgcn_sched_barrier(0);
    __builtin_amdgcn_s_barrier();
    __builtin_amdgcn_sched_barrier(0);

    const char* A0p = (const char*)&As[c][0][0];
    const char* A1p = (const char*)&As[c][1][0];
    const char* B0p = (const char*)&Bs[c][0][0];
    const char* B1p = (const char*)&Bs[c][1][0];

    short8 aq0[8], aq1[8], bq0[4], bq1[4];

    auto rdA = [&](const char* p, short8* dst) {
#pragma unroll
      for (int mf = 0; mf < 4; ++mf)
#pragma unroll
        for (int ks = 0; ks < 2; ++ks) {
          const int vr = wm * 64 + mf * 16 + fr;
          const int byte = ((vr * 64 + ks * 32 + fkE) * 2) ^ fxor;
          dst[mf * 2 + ks] = *reinterpret_cast<const short8*>(p + byte);
        }
    };
    auto rdB = [&](const char* p, short8* dst) {
#pragma unroll
      for (int nf = 0; nf < 2; ++nf)
#pragma unroll
        for (int ks = 0; ks < 2; ++ks) {
          const int vr = wn * 32 + nf * 16 + fr;
          const int byte = ((vr * 64 + ks * 32 + fkE) * 2) ^ fxor;
          dst[nf * 2 + ks] = *reinterpret_cast<const short8*>(p + byte);
        }
    };
    auto quad = [&](short8* a, short8* b, int mh, int nh) {
      __builtin_amdgcn_s_setprio(1);
#pragma unroll
      for (int mf = 0; mf < 4; ++mf)
#pragma unroll
        for (int nf = 0; nf < 2; ++nf)
#pragma unroll
          for (int ks = 0; ks < 2; ++ks)
            acc[mh * 4 + mf][nh * 2 + nf] = __builtin_amdgcn_mfma_f32_16x16x32_bf16(
                a[mf * 2 + ks], b[nf * 2 + ks], acc[mh * 4 + mf][nh * 2 + nf], 0, 0, 0);
      __builtin_amdgcn_s_setprio(0);
    };

    // ---- P1: read aq0,bq0 (slots A0,B0) ; stage B1(t+1) -> buf c^1 ----
    rdA(A0p, aq0);
    rdB(B0p, bq0);
    if (t + 1 < NT) STGB(&Bs[c ^ 1][1][0], t + 1, 1);
    __builtin_amdgcn_sched_barrier(0);
    __builtin_amdgcn_s_barrier();
    asm volatile("s_waitcnt lgkmcnt(0)" ::: "memory");
    __builtin_amdgcn_sched_barrier(0);
    quad(aq0, bq0, 0, 0);
    __builtin_amdgcn_sched_barrier(0);
    __builtin_amdgcn_s_barrier();
    __builtin_amdgcn_sched_barrier(0);

    // ---- P2: read bq1 (slot B1) ; stage A0(t+2) -> buf c (A0 last read P1) ----
    rdB(B1p, bq1);
    if (t + 2 < NT) STGA(&As[c][0][0], t + 2, 0);
    __builtin_amdgcn_sched_barrier(0);
    __builtin_amdgcn_s_barrier();
    asm volatile("s_waitcnt lgkmcnt(0)" ::: "memory");
    __builtin_amdgcn_sched_barrier(0);
    quad(aq0, bq1, 0, 1);
    __builtin_amdgcn_sched_barrier(0);
    __builtin_amdgcn_s_barrier();
    __builtin_amdgcn_sched_barrier(0);

    // ---- P3: read aq1 (slot A1) ; stage B0(t+2) -> buf c (B0 last read P1) ----
    rdA(A1p, aq1);
    if (t + 2 < NT) STGB(&Bs[c][0][0], t + 2, 0);
    __builtin_amdgcn_sched_barrier(0);
    __builtin_amdgcn_s_barrier();
    asm volatile("s_waitcnt lgkmcnt(0)" ::: "memory");
    __builtin_amdgcn_sched_barrier(0);
    quad(aq1, bq1, 1, 1);
    __builtin_amdgcn_sched_barrier(0);
    __builtin_amdgcn_s_barrier();
    __builtin_amdgcn_sched_barrier(0);

    // ---- P4: stage A1(t+2) -> buf c (A1 last read P3) ; no new reads ----
    if (t + 2 < NT) STGA(&As[c][1][0], t + 2, 1);
    __builtin_amdgcn_sched_barrier(0);
    __builtin_amdgcn_s_barrier();
    __builtin_amdgcn_sched_barrier(0);
    quad(aq1, bq0, 1, 0);
    // loop-top boundary barrier follows
  }
#undef STGA
#undef STGB

  // Epilogue. C/D layout: col = lane&15, row = (lane>>4)*4 + reg  [m89/m91]
  const long rowBase = (long)blockIdx.x * 256 + wm * 128 + ((lane >> 4) << 2);
  const int colBase = (int)blockIdx.y * 256 + wn * 64 + (lane & 15);
#pragma unroll
  for (int mf = 0; mf < 8; ++mf) {
#pragma unroll
    for (int nf = 0; nf < 4; ++nf) {
      const int col = colBase + nf * 16;
#pragma unroll
      for (int i = 0; i < 4; ++i) {
        const long r = rowBase + mf * 16 + i;
        float vv = acc[mf][nf][i];
        if constexpr (EPI == 0) {
          outB[r * (long)ldOut + col] = f2b(vv);
        } else if constexpr (EPI == 1) {
          oF[(long)zz * oBatch + r * (long)ldOut + col] = vv;
        } else if constexpr (EPI == 2) {
          outB[r * (long)ldOut + col] = f2b(gelu_fast(vv + bias[col]));
        } else {
          const long idx = r * (long)ldOut + col;
          outF[idx] = vv + bias[col] + b2f(residB[idx]);
        }
      }
    }
  }
}

// ---------------------------------------------------------------------------
// combine_ln: quadrant combine + x residual + row LayerNorm, fused.
//   attn[k,d]=u-v; [k,768-d]=u+v; [4096-k,d]=u+v; [4096-k,768-d]=u-v
// Block (k,z) owns FULL rows k and 4096-k; block-reduces mean/var for both,
// writes out1 bf16 directly. y1 is never materialized.
// ---------------------------------------------------------------------------
__global__ __launch_bounds__(256) void combine_ln(
    const float* __restrict__ u, const float* __restrict__ v,
    const float* __restrict__ x, const float* __restrict__ gamma,
    const float* __restrict__ beta, unsigned short* __restrict__ o1b) {
  const int k = blockIdx.x;            // 0..2048
  const int z = blockIdx.y;            // 0..7
  const long ub = ((long)z * 2304 + k) * 512;
  const long base = (long)z * 4096L * 768;
  const long rowA = base + (long)k * 768;
  const long rowB = base + (long)(4096 - k) * 768;
  const bool doRowB = (k != 0) && (k != 2048);
  const int t = threadIdx.x;

  // it=0: d=t (0..255); it=1: d=t+256 (active when <=384)
  float vA0[2], vA1[2], vB0[2], vB1[2];
  float sA = 0.f, qA = 0.f, sB = 0.f, qB = 0.f;
#pragma unroll
  for (int it = 0; it < 2; ++it) {
    const int d = t + it * 256;
    if (d <= 384) {
      const float uu = u[ub + d];
      const float vv = v[ub + d];
      const float a1 = uu - vv;
      const float a2 = uu + vv;
      const int dd = 768 - d;
      const bool colB = (d != 0) && (d != 384);
      float va = a1 + x[rowA + d];
      vA0[it] = va; sA += va; qA += va * va;
      if (colB) { float w = a2 + x[rowA + dd]; vA1[it] = w; sA += w; qA += w * w; }
      if (doRowB) {
        float wb = a2 + x[rowB + d];
        vB0[it] = wb; sB += wb; qB += wb * wb;
        if (colB) { float w2 = a1 + x[rowB + dd]; vB1[it] = w2; sB += w2; qB += w2 * w2; }
      }
    }
  }
#pragma unroll
  for (int off = 32; off > 0; off >>= 1) {
    sA += __shfl_down(sA, off, 64); qA += __shfl_down(qA, off, 64);
    sB += __shfl_down(sB, off, 64); qB += __shfl_down(qB, off, 64);
  }
  __shared__ float red[4][4];
  if ((t & 63) == 0) {
    red[t >> 6][0] = sA; red[t >> 6][1] = qA;
    red[t >> 6][2] = sB; red[t >> 6][3] = qB;
  }
  __syncthreads();
  const float SA = red[0][0] + red[1][0] + red[2][0] + red[3][0];
  const float QA = red[0][1] + red[1][1] + red[2][1] + red[3][1];
  const float SB = red[0][2] + red[1][2] + red[2][2] + red[3][2];
  const float QB = red[0][3] + red[1][3] + red[2][3] + red[3][3];
  const float muA = SA * (1.0f / 768.0f);
  const float rsA = rsqrtf(QA * (1.0f / 768.0f) - muA * muA + 1e-6f);
  const float muB = SB * (1.0f / 768.0f);
  const float rsB = rsqrtf(QB * (1.0f / 768.0f) - muB * muB + 1e-6f);

#pragma unroll
  for (int it = 0; it < 2; ++it) {
    const int d = t + it * 256;
    if (d <= 384) {
      const int dd = 768 - d;
      const bool colB = (d != 0) && (d != 384);
      const float g0 = gamma[d], b0 = beta[d];
      o1b[rowA + d] = f2b((vA0[it] - muA) * rsA * g0 + b0);
      if (colB) o1b[rowA + dd] = f2b((vA1[it] - muA) * rsA * gamma[dd] + beta[dd]);
      if (doRowB) {
        o1b[rowB + d] = f2b((vB0[it] - muB) * rsB * g0 + b0);
        if (colB) o1b[rowB + dd] = f2b((vB1[it] - muB) * rsB * gamma[dd] + beta[dd]);
      }
    }
  }
}

// ---------------------------------------------------------------------------
// Row LayerNorm over D=768 (fp32 in/out, used for LN2 in-place).
// ---------------------------------------------------------------------------
__global__ __launch_bounds__(256) void ln_row_f32(
    const float* __restrict__ in, const float* __restrict__ gamma,
    const float* __restrict__ beta, float* __restrict__ outF) {
  const long row = blockIdx.x;
  const float* p = in + row * 768;
  const int t = threadIdx.x;
  const float v0 = p[t], v1 = p[t + 256], v2 = p[t + 512];
  float s = v0 + v1 + v2;
  float q = v0 * v0 + v1 * v1 + v2 * v2;
#pragma unroll
  for (int off = 32; off > 0; off >>= 1) {
    s += __shfl_down(s, off, 64);
    q += __shfl_down(q, off, 64);
  }
  __shared__ float ss[4], sq[4];
  if ((t & 63) == 0) { ss[t >> 6] = s; sq[t >> 6] = q; }
  __syncthreads();
  const float S = ss[0] + ss[1] + ss[2] + ss[3];
  const float Q = sq[0] + sq[1] + sq[2] + sq[3];
  const float mu = S * (1.0f / 768.0f);
  const float var = Q * (1.0f / 768.0f) - mu * mu;
  const float rs = rsqrtf(var + 1e-6f);
  outF[row * 768 + t]       = (v0 - mu) * rs * gamma[t] + beta[t];
  outF[row * 768 + t + 256] = (v1 - mu) * rs * gamma[t + 256] + beta[t + 256];
  outF[row * 768 + t + 512] = (v2 - mu) * rs * gamma[t + 512] + beta[t + 512];
}

// ---------------------------------------------------------------------------

extern "C" void kernel_launch(void* const* d_in, const int* in_sizes, int n_in,
                              void* d_out, int out_size, void* d_ws, size_t ws_size,
                              hipStream_t stream) {
  const float* x   = (const float*)d_in[0];   // (8,4096,768)
  const float* W1  = (const float*)d_in[1];   // (768,3072)
  const float* b1  = (const float*)d_in[2];   // (3072)
  const float* W2  = (const float*)d_in[3];   // (3072,768)
  const float* b2  = (const float*)d_in[4];   // (768)
  const float* g1  = (const float*)d_in[5];
  const float* be1 = (const float*)d_in[6];
  const float* g2  = (const float*)d_in[7];
  const float* be2 = (const float*)d_in[8];
  float* out = (float*)d_out;                 // fp32, also y2 scratch

  char* ws = (char*)d_ws;
  unsigned short* xb   = (unsigned short*)(ws + 0L);           //  50,331,648
  unsigned short* Bt1  = (unsigned short*)(ws + 50331648L);    //   1,572,864
  unsigned short* Au   = (unsigned short*)(ws + 51904512L);    //  18,874,368
  unsigned short* Av   = (unsigned short*)(ws + 70778880L);    //  18,874,368
  unsigned short* T    = (unsigned short*)(ws + 89653248L);    //  67,108,864 -> ends 156,762,112
  unsigned short* BtUV = (unsigned short*)(ws + 156762112L);   //  67,108,864 -> ends 223,870,976
  float*          u    = (float*)        (ws + 0L);            //  37,748,736 (aliases xb; dead after GEMM1)
  float*          v    = (float*)        (ws + 89653248L);     //  37,748,736 (aliases T; dead after transpose_T)
  unsigned short* H    = (unsigned short*)(ws + 0L);           // 201,326,592 (aliases all FFT buffers, dead by GEMM3)
  unsigned short* o1b  = (unsigned short*)(ws + 201326592L);   //  50,331,648 (overlaps BtUV tail, dead by combine_ln)
  unsigned short* W1t  = (unsigned short*)(ws + 251658240L);   //   4,718,592
  unsigned short* W2t  = (unsigned short*)(ws + 256376832L);   //   4,718,592
  // total ws needed: 261,095,424 bytes (~249 MiB)

  // --- prep ---
  f32_to_bf16_vec<<<24576, 256, 0, stream>>>(x, xb);
  fill_bt1<<<3072, 256, 0, stream>>>(Bt1);
  fill_auv<<<36864, 256, 0, stream>>>(Au, Av);                 // 2304*4096/256
  transpose_f32_to_bf16<<<dim3(96, 24), 256, 0, stream>>>(W1, W1t, 768, 3072);
  transpose_f32_to_bf16<<<dim3(24, 96), 256, 0, stream>>>(W2, W2t, 3072, 768);

  // --- GEMM1: T = xb @ Bt1^T (row-major, ld 1024) ---
  gemm256<0><<<dim3(128, 4, 1), 512, 0, stream>>>(
      xb, Bt1, nullptr, nullptr, 768, 768, 768, 0L, 0L, 999,
      nullptr, nullptr, T, nullptr, nullptr, 1024);

  // --- transpose T -> BtU/BtV ([b][d][s]) ---
  transpose_T<<<dim3(128, 32, 8), 256, 0, stream>>>(T, BtUV);

  // --- GEMM_uv fused (z<8: u = C_S @ Tc; z>=8: v = S_S @ Ts) ---
  gemm256<1><<<dim3(9, 2, 16), 512, 0, stream>>>(
      Au, BtUV, Av, BtUV + 16777216L, 4096, 4096, 4096,
      512L * 4096L, 2304L * 512L, 8,
      u, v, nullptr, nullptr, nullptr, 512);

  // --- combine quadrants + x residual + LN1 -> out1 (bf16), fused ---
  combine_ln<<<dim3(2049, 8), 256, 0, stream>>>(u, v, x, g1, be1, o1b);

  // --- GEMM3: H = gelu(out1 @ W1 + b1) ---
  gemm256<2><<<dim3(128, 12, 1), 512, 0, stream>>>(
      o1b, W1t, nullptr, nullptr, 768, 768, 768, 0L, 0L, 999,
      nullptr, nullptr, H, b1, nullptr, 3072);

  // --- GEMM4: y2 = H @ W2 + b2 + out1 -> d_out ---
  gemm256<3><<<dim3(128, 3, 1), 512, 0, stream>>>(
      H, W2t, nullptr, nullptr, 3072, 3072, 3072, 0L, 0L, 999,
      out, nullptr, nullptr, b2, o1b, 768);

  // --- LN2 in-place ---
  ln_row_f32<<<32768, 256, 0, stream>>>(out, g2, be2, out);
}

// Round 8
// 873.638 us; speedup vs baseline: 1.3965x; 1.0029x over previous
//
#include <hip/hip_runtime.h>
#include <cstdint>

// FNet block on MI355X.
//   attn = Re(FFT2(x)) via bf16 MFMA matmuls + real-input quadrant symmetry:
//     GEMM1: T[r][0:512]=Tc, T[r][512:1024]=Ts   (M=32768, N=1024, K=768)
//     transpose_T: BtU[b][d][s]=Tc[s,d], BtV[b][d][s]=Ts[s,d]
//     GEMM_uv (fused, z=0..15): u (cos) / v (sin), M=2304(pad), N=512, K=4096
//     combine_ln: quadrant-combine u+-v, +x residual, FUSED row-LayerNorm -> out1 bf16
//   GEMM3: H = gelu(out1 @ W1 + b1)       (M=32768, N=3072, K=768)  [fast tanh-gelu]
//   GEMM4: y2 = H @ W2 + b2 + out1        (M=32768, N=768, K=3072)
//   LN2 in-place on d_out.
//
// GEMM core (K-loop unchanged from round 6/7, verified): 256x256 tile, BK=64,
// 8 waves, LDS 2 buf x 2 half-slots x (A,B) = 128 KiB, 4-phase/K-tile
// interleaved schedule, counted vmcnt(6), T2 swizzle, setprio.
// NEW (round 8): 1D launch + XCD-gather block remap (l = (p%8)*(total/8)+p/8,
// bijective since total%8==0) + N-fastest decode, so co-resident blocks on an
// XCD share the same A-panel (L2 hit) and B/H stream from L3. Targets the
// measured 444 MB redundant fetch in GEMM3/GEMM4.

typedef __attribute__((ext_vector_type(8))) short short8;
typedef __attribute__((ext_vector_type(4))) float f32x4;

__device__ __forceinline__ unsigned short f2b(float f) {
  union { float f; uint32_t u; } c; c.f = f;
  uint32_t u = c.u;
  u += 0x7FFFu + ((u >> 16) & 1u);   // round-to-nearest-even
  return (unsigned short)(u >> 16);
}
__device__ __forceinline__ float b2f(unsigned short h) {
  union { uint32_t u; float f; } c; c.u = ((uint32_t)h) << 16;
  return c.f;
}

// fast GELU (tanh form), ~9 VALU: g = x*E/(E+1), E = exp(2*inner),
// inner = 0.79788456*x*(1 + 0.044715*x^2). max |err vs exact erf-gelu| ~3e-3.
__device__ __forceinline__ float gelu_fast(float x) {
  float x2 = x * x;
  float inner = x * fmaf(x2, 0.0356774081f, 0.7978845608f);
  float zz = fminf(inner * 2.885390082f, 80.0f);   // exp2 arg = 2*inner*log2(e)
  float E, r;
  asm("v_exp_f32 %0, %1" : "=v"(E) : "v"(zz));
  float den = E + 1.0f;
  asm("v_rcp_f32 %0, %1" : "=v"(r) : "v"(den));
  return x * E * r;
}

// ---------------------------------------------------------------------------
// Fill / convert kernels (unchanged, verified)
// ---------------------------------------------------------------------------

__global__ __launch_bounds__(256) void f32_to_bf16_vec(
    const float* __restrict__ in, unsigned short* __restrict__ out) {
  long i = (long)blockIdx.x * 256 + threadIdx.x;   // element-of-4 index
  float4 v = reinterpret_cast<const float4*>(in)[i];
  ushort4 o;
  o.x = f2b(v.x); o.y = f2b(v.y); o.z = f2b(v.z); o.w = f2b(v.w);
  reinterpret_cast<ushort4*>(out)[i] = o;
}

// Bt1: (1024 x 768). Row j<512: cos(2*pi*j*n/768); row j>=512: sin(2*pi*(j-512)*n/768).
__global__ __launch_bounds__(256) void fill_bt1(unsigned short* __restrict__ Bt1) {
  int i = blockIdx.x * 256 + threadIdx.x;          // < 1024*768
  int j = i / 768;
  int n = i - j * 768;
  int jj = j & 511;
  int m = (jj * n) % 768;
  float ang = (float)m * (6.283185307179586f / 768.0f);
  Bt1[i] = f2b((j < 512) ? cosf(ang) : sinf(ang));
}

// Au[k][s] = cos(2*pi*k*s/4096), Av[k][s] = sin(...), k=0..2303 (padded), s=0..4095.
__global__ __launch_bounds__(256) void fill_auv(
    unsigned short* __restrict__ Au, unsigned short* __restrict__ Av) {
  long i = (long)blockIdx.x * 256 + threadIdx.x;   // < 2304*4096
  int k = (int)(i >> 12);
  int s = (int)(i & 4095);
  int mm = (k * s) & 4095;
  float ang = (float)mm * (6.283185307179586f / 4096.0f);
  Au[i] = f2b(cosf(ang));
  Av[i] = f2b(sinf(ang));
}

// out[c][r] = bf16(in[r][c]); R,C multiples of 32  (for W1, W2)
__global__ __launch_bounds__(256) void transpose_f32_to_bf16(
    const float* __restrict__ in, unsigned short* __restrict__ out, int R, int C) {
  __shared__ float tile[32][33];
  const int c0 = blockIdx.x * 32;
  const int r0 = blockIdx.y * 32;
  const int tx = threadIdx.x & 31;
  const int ty = threadIdx.x >> 5;   // 0..7
#pragma unroll
  for (int i = ty; i < 32; i += 8)
    tile[i][tx] = in[(long)(r0 + i) * C + c0 + tx];
  __syncthreads();
#pragma unroll
  for (int i = ty; i < 32; i += 8)
    out[(long)(c0 + i) * R + r0 + tx] = f2b(tile[tx][i]);
}

// BtUV[(d<512?0:HALF) + (b*512 + (d&511))*4096 + s] = T[(b*4096+s)*1024 + d]
__global__ __launch_bounds__(256) void transpose_T(
    const unsigned short* __restrict__ T, unsigned short* __restrict__ BtUV) {
  __shared__ unsigned short tile[32][33];
  const int s0 = blockIdx.x * 32;
  const int d0 = blockIdx.y * 32;
  const int b  = blockIdx.z;
  const int tx = threadIdx.x & 31;
  const int ty = threadIdx.x >> 5;   // 0..7
  const unsigned short* Tb = T + ((long)b * 4096 + s0) * 1024 + d0;
#pragma unroll
  for (int i = ty; i < 32; i += 8)
    tile[i][tx] = Tb[(long)i * 1024 + tx];       // tile[s_local][d_local]
  __syncthreads();
#pragma unroll
  for (int i = ty; i < 32; i += 8) {
    const int d = d0 + i;
    const long off = (d < 512) ? 0L : 16777216L;
    BtUV[off + ((long)b * 512 + (d & 511)) * 4096 + s0 + tx] = tile[tx][i];
  }
}

// ---------------------------------------------------------------------------
// GEMM256 with phase-interleaved pipeline + XCD-gather block remap.
// Launched with a 1D grid of NX*NY*NZ blocks (must be divisible by 8).
// Decode: l = (p%8)*(total/8) + p/8;  by = l%NY (fastest), bx = (l/NY)%NX,
// bz = l/(NY*NX). Consecutive l (co-resident on one XCD) share the A-panel.
// Epilogues: 0 = bf16 store (GEMM1->T); 1 = fp32 z-batched store, z>=zSplit
//            switches to (A2p,Bt2p,outF2) operand set (fused GEMM_u/GEMM_v);
//            2 = +bias, fast gelu, bf16 (GEMM3->H); 3 = +bias+bf16resid, fp32.
// M,N multiples of 256; K multiple of 64; K/64 >= 4.
// ---------------------------------------------------------------------------

template <int EPI>
__global__ __launch_bounds__(512, 2) void gemm256(
    const unsigned short* __restrict__ A, const unsigned short* __restrict__ Bt,
    const unsigned short* __restrict__ A2p, const unsigned short* __restrict__ Bt2p,
    int K, int lda, int ldb, long bBatch, long oBatch, int zSplit,
    int NX, int NY,
    float* __restrict__ outF, float* __restrict__ outF2,
    unsigned short* __restrict__ outB,
    const float* __restrict__ bias, const unsigned short* __restrict__ residB,
    int ldOut) {
  __shared__ __align__(16) unsigned short As[2][2][8192];   // [buf][slot][16KB]
  __shared__ __align__(16) unsigned short Bs[2][2][8192];

  const int tid = threadIdx.x;
  const int lane = tid & 63;
  const int wid = tid >> 6;          // 0..7
  const int wm = wid >> 2;           // 0..1
  const int wn = wid & 3;            // 0..3

  // ---- XCD-gather remap + N-fastest decode ----
  const int p = (int)blockIdx.x;
  const int l = (p & 7) * ((int)gridDim.x >> 3) + (p >> 3);
  const int by = l % NY;
  const int lx = l / NY;
  const int bx = lx % NX;
  int zz = lx / NX;

  const unsigned short* Ax = A;
  const unsigned short* Bx = Bt;
  float* oF = outF;
  if (EPI == 1 && zz >= zSplit) { Ax = A2p; Bx = Bt2p; oF = outF2; zz -= zSplit; }

  const unsigned short* Ab = Ax + (long)bx * 256 * lda;
  const unsigned short* Bb = Bx + (long)zz * bBatch + (long)by * 256 * ldb;

  const int NT = K >> 6;             // #K-tiles (>= 12 for all our shapes)

  // Staging: linear LDS dest, T2 swizzle pre-applied to per-lane GLOBAL column.
  const int srow = lane >> 3;                      // row within 8-row region
  const int scolE = ((lane & 7) ^ srow) << 3;      // pre-swizzled col (elems)

  // A-slot h: virtual row vr = wm*64 + rr  ->  global row wm*128 + h*64 + rr
#define STGA(dst, kt, h) do {                                                          \
    _Pragma("unroll")                                                                  \
    for (int i_ = 0; i_ < 2; ++i_) {                                                   \
      const int reg_ = i_ * 8 + wid;                                                   \
      const int vr_ = reg_ * 8 + srow;                                                 \
      const int grow_ = ((vr_ >> 6) << 7) + (h) * 64 + (vr_ & 63);                     \
      __builtin_amdgcn_global_load_lds(                                                \
        (const __attribute__((address_space(1))) void*)(Ab + (long)grow_ * lda + (long)(kt) * 64 + scolE), \
        (__attribute__((address_space(3))) void*)((dst) + reg_ * 512), 16, 0, 0);      \
    } } while (0)
  // B-slot h: virtual row vr = wn*32 + rr  ->  global row wn*64 + h*32 + rr
#define STGB(dst, kt, h) do {                                                          \
    _Pragma("unroll")                                                                  \
    for (int i_ = 0; i_ < 2; ++i_) {                                                   \
      const int reg_ = i_ * 8 + wid;                                                   \
      const int vr_ = reg_ * 8 + srow;                                                 \
      const int grow_ = ((vr_ >> 5) << 6) + (h) * 32 + (vr_ & 31);                     \
      __builtin_amdgcn_global_load_lds(                                                \
        (const __attribute__((address_space(1))) void*)(Bb + (long)grow_ * ldb + (long)(kt) * 64 + scolE), \
        (__attribute__((address_space(3))) void*)((dst) + reg_ * 512), 16, 0, 0);      \
    } } while (0)

  const int fr = lane & 15;          // frag row within 16
  const int fkE = (lane >> 4) << 3;  // k-offset elems (0,8,16,24)
  const int fxor = (lane & 7) << 4;  // T2 swizzle XOR (lane-constant)

  f32x4 acc[8][4] = {};

  // prologue: tile0 all 4 slots + tile1 {A0, A1, B0} = 7 stages (14 loads)
  STGA(&As[0][0][0], 0, 0);
  STGA(&As[0][1][0], 0, 1);
  STGB(&Bs[0][0][0], 0, 0);
  STGB(&Bs[0][1][0], 0, 1);
  STGA(&As[1][0][0], 1, 0);
  STGA(&As[1][1][0], 1, 1);
  STGB(&Bs[1][0][0], 1, 0);

  for (int t = 0; t < NT; ++t) {
    const int c = t & 1;

    // ---- tile boundary: tile t's 4 slots landed; 3 newest stages in flight ----
    if (t + 1 < NT) { asm volatile("s_waitcnt vmcnt(6)" ::: "memory"); }
    else            { asm volatile("s_waitcnt vmcnt(0)" ::: "memory"); }
    __builtin_amdgcn_sched_barrier(0);
    __builtin_amdgcn_s_barrier();
    __builtin_amdgcn_sched_barrier(0);

    const char* A0p = (const char*)&As[c][0][0];
    const char* A1p = (const char*)&As[c][1][0];
    const char* B0p = (const char*)&Bs[c][0][0];
    const char* B1p = (const char*)&Bs[c][1][0];

    short8 aq0[8], aq1[8], bq0[4], bq1[4];

    auto rdA = [&](const char* p_, short8* dst) {
#pragma unroll
      for (int mf = 0; mf < 4; ++mf)
#pragma unroll
        for (int ks = 0; ks < 2; ++ks) {
          const int vr = wm * 64 + mf * 16 + fr;
          const int byte = ((vr * 64 + ks * 32 + fkE) * 2) ^ fxor;
          dst[mf * 2 + ks] = *reinterpret_cast<const short8*>(p_ + byte);
        }
    };
    auto rdB = [&](const char* p_, short8* dst) {
#pragma unroll
      for (int nf = 0; nf < 2; ++nf)
#pragma unroll
        for (int ks = 0; ks < 2; ++ks) {
          const int vr = wn * 32 + nf * 16 + fr;
          const int byte = ((vr * 64 + ks * 32 + fkE) * 2) ^ fxor;
          dst[nf * 2 + ks] = *reinterpret_cast<const short8*>(p_ + byte);
        }
    };
    auto quad = [&](short8* a, short8* b, int mh, int nh) {
      __builtin_amdgcn_s_setprio(1);
#pragma unroll
      for (int mf = 0; mf < 4; ++mf)
#pragma unroll
        for (int nf = 0; nf < 2; ++nf)
#pragma unroll
          for (int ks = 0; ks < 2; ++ks)
            acc[mh * 4 + mf][nh * 2 + nf] = __builtin_amdgcn_mfma_f32_16x16x32_bf16(
                a[mf * 2 + ks], b[nf * 2 + ks], acc[mh * 4 + mf][nh * 2 + nf], 0, 0, 0);
      __builtin_amdgcn_s_setprio(0);
    };

    // ---- P1: read aq0,bq0 (slots A0,B0) ; stage B1(t+1) -> buf c^1 ----
    rdA(A0p, aq0);
    rdB(B0p, bq0);
    if (t + 1 < NT) STGB(&Bs[c ^ 1][1][0], t + 1, 1);
    __builtin_amdgcn_sched_barrier(0);
    __builtin_amdgcn_s_barrier();
    asm volatile("s_waitcnt lgkmcnt(0)" ::: "memory");
    __builtin_amdgcn_sched_barrier(0);
    quad(aq0, bq0, 0, 0);
    __builtin_amdgcn_sched_barrier(0);
    __builtin_amdgcn_s_barrier();
    __builtin_amdgcn_sched_barrier(0);

    // ---- P2: read bq1 (slot B1) ; stage A0(t+2) -> buf c (A0 last read P1) ----
    rdB(B1p, bq1);
    if (t + 2 < NT) STGA(&As[c][0][0], t + 2, 0);
    __builtin_amdgcn_sched_barrier(0);
    __builtin_amdgcn_s_barrier();
    asm volatile("s_waitcnt lgkmcnt(0)" ::: "memory");
    __builtin_amdgcn_sched_barrier(0);
    quad(aq0, bq1, 0, 1);
    __builtin_amdgcn_sched_barrier(0);
    __builtin_amdgcn_s_barrier();
    __builtin_amdgcn_sched_barrier(0);

    // ---- P3: read aq1 (slot A1) ; stage B0(t+2) -> buf c (B0 last read P1) ----
    rdA(A1p, aq1);
    if (t + 2 < NT) STGB(&Bs[c][0][0], t + 2, 0);
    __builtin_amdgcn_sched_barrier(0);
    __builtin_amdgcn_s_barrier();
    asm volatile("s_waitcnt lgkmcnt(0)" ::: "memory");
    __builtin_amdgcn_sched_barrier(0);
    quad(aq1, bq1, 1, 1);
    __builtin_amdgcn_sched_barrier(0);
    __builtin_amdgcn_s_barrier();
    __builtin_amdgcn_sched_barrier(0);

    // ---- P4: stage A1(t+2) -> buf c (A1 last read P3) ; no new reads ----
    if (t + 2 < NT) STGA(&As[c][1][0], t + 2, 1);
    __builtin_amdgcn_sched_barrier(0);
    __builtin_amdgcn_s_barrier();
    __builtin_amdgcn_sched_barrier(0);
    quad(aq1, bq0, 1, 0);
    // loop-top boundary barrier follows
  }
#undef STGA
#undef STGB

  // Epilogue. C/D layout: col = lane&15, row = (lane>>4)*4 + reg  [m89/m91]
  const long rowBase = (long)bx * 256 + wm * 128 + ((lane >> 4) << 2);
  const int colBase = by * 256 + wn * 64 + (lane & 15);
#pragma unroll
  for (int mf = 0; mf < 8; ++mf) {
#pragma unroll
    for (int nf = 0; nf < 4; ++nf) {
      const int col = colBase + nf * 16;
#pragma unroll
      for (int i = 0; i < 4; ++i) {
        const long r = rowBase + mf * 16 + i;
        float vv = acc[mf][nf][i];
        if constexpr (EPI == 0) {
          outB[r * (long)ldOut + col] = f2b(vv);
        } else if constexpr (EPI == 1) {
          oF[(long)zz * oBatch + r * (long)ldOut + col] = vv;
        } else if constexpr (EPI == 2) {
          outB[r * (long)ldOut + col] = f2b(gelu_fast(vv + bias[col]));
        } else {
          const long idx = r * (long)ldOut + col;
          outF[idx] = vv + bias[col] + b2f(residB[idx]);
        }
      }
    }
  }
}

// ---------------------------------------------------------------------------
// combine_ln: quadrant combine + x residual + row LayerNorm, fused.
// Block (k,z) owns FULL rows k and 4096-k; writes out1 bf16 directly.
// ---------------------------------------------------------------------------
__global__ __launch_bounds__(256) void combine_ln(
    const float* __restrict__ u, const float* __restrict__ v,
    const float* __restrict__ x, const float* __restrict__ gamma,
    const float* __restrict__ beta, unsigned short* __restrict__ o1b) {
  const int k = blockIdx.x;            // 0..2048
  const int z = blockIdx.y;            // 0..7
  const long ub = ((long)z * 2304 + k) * 512;
  const long base = (long)z * 4096L * 768;
  const long rowA = base + (long)k * 768;
  const long rowB = base + (long)(4096 - k) * 768;
  const bool doRowB = (k != 0) && (k != 2048);
  const int t = threadIdx.x;

  float vA0[2], vA1[2], vB0[2], vB1[2];
  float sA = 0.f, qA = 0.f, sB = 0.f, qB = 0.f;
#pragma unroll
  for (int it = 0; it < 2; ++it) {
    const int d = t + it * 256;
    if (d <= 384) {
      const float uu = u[ub + d];
      const float vv = v[ub + d];
      const float a1 = uu - vv;
      const float a2 = uu + vv;
      const int dd = 768 - d;
      const bool colB = (d != 0) && (d != 384);
      float va = a1 + x[rowA + d];
      vA0[it] = va; sA += va; qA += va * va;
      if (colB) { float w = a2 + x[rowA + dd]; vA1[it] = w; sA += w; qA += w * w; }
      if (doRowB) {
        float wb = a2 + x[rowB + d];
        vB0[it] = wb; sB += wb; qB += wb * wb;
        if (colB) { float w2 = a1 + x[rowB + dd]; vB1[it] = w2; sB += w2; qB += w2 * w2; }
      }
    }
  }
#pragma unroll
  for (int off = 32; off > 0; off >>= 1) {
    sA += __shfl_down(sA, off, 64); qA += __shfl_down(qA, off, 64);
    sB += __shfl_down(sB, off, 64); qB += __shfl_down(qB, off, 64);
  }
  __shared__ float red[4][4];
  if ((t & 63) == 0) {
    red[t >> 6][0] = sA; red[t >> 6][1] = qA;
    red[t >> 6][2] = sB; red[t >> 6][3] = qB;
  }
  __syncthreads();
  const float SA = red[0][0] + red[1][0] + red[2][0] + red[3][0];
  const float QA = red[0][1] + red[1][1] + red[2][1] + red[3][1];
  const float SB = red[0][2] + red[1][2] + red[2][2] + red[3][2];
  const float QB = red[0][3] + red[1][3] + red[2][3] + red[3][3];
  const float muA = SA * (1.0f / 768.0f);
  const float rsA = rsqrtf(QA * (1.0f / 768.0f) - muA * muA + 1e-6f);
  const float muB = SB * (1.0f / 768.0f);
  const float rsB = rsqrtf(QB * (1.0f / 768.0f) - muB * muB + 1e-6f);

#pragma unroll
  for (int it = 0; it < 2; ++it) {
    const int d = t + it * 256;
    if (d <= 384) {
      const int dd = 768 - d;
      const bool colB = (d != 0) && (d != 384);
      const float g0 = gamma[d], b0 = beta[d];
      o1b[rowA + d] = f2b((vA0[it] - muA) * rsA * g0 + b0);
      if (colB) o1b[rowA + dd] = f2b((vA1[it] - muA) * rsA * gamma[dd] + beta[dd]);
      if (doRowB) {
        o1b[rowB + d] = f2b((vB0[it] - muB) * rsB * g0 + b0);
        if (colB) o1b[rowB + dd] = f2b((vB1[it] - muB) * rsB * gamma[dd] + beta[dd]);
      }
    }
  }
}

// ---------------------------------------------------------------------------
// Row LayerNorm over D=768 (fp32 in/out, used for LN2 in-place).
// ---------------------------------------------------------------------------
__global__ __launch_bounds__(256) void ln_row_f32(
    const float* __restrict__ in, const float* __restrict__ gamma,
    const float* __restrict__ beta, float* __restrict__ outF) {
  const long row = blockIdx.x;
  const float* p = in + row * 768;
  const int t = threadIdx.x;
  const float v0 = p[t], v1 = p[t + 256], v2 = p[t + 512];
  float s = v0 + v1 + v2;
  float q = v0 * v0 + v1 * v1 + v2 * v2;
#pragma unroll
  for (int off = 32; off > 0; off >>= 1) {
    s += __shfl_down(s, off, 64);
    q += __shfl_down(q, off, 64);
  }
  __shared__ float ss[4], sq[4];
  if ((t & 63) == 0) { ss[t >> 6] = s; sq[t >> 6] = q; }
  __syncthreads();
  const float S = ss[0] + ss[1] + ss[2] + ss[3];
  const float Q = sq[0] + sq[1] + sq[2] + sq[3];
  const float mu = S * (1.0f / 768.0f);
  const float var = Q * (1.0f / 768.0f) - mu * mu;
  const float rs = rsqrtf(var + 1e-6f);
  outF[row * 768 + t]       = (v0 - mu) * rs * gamma[t] + beta[t];
  outF[row * 768 + t + 256] = (v1 - mu) * rs * gamma[t + 256] + beta[t + 256];
  outF[row * 768 + t + 512] = (v2 - mu) * rs * gamma[t + 512] + beta[t + 512];
}

// ---------------------------------------------------------------------------

extern "C" void kernel_launch(void* const* d_in, const int* in_sizes, int n_in,
                              void* d_out, int out_size, void* d_ws, size_t ws_size,
                              hipStream_t stream) {
  const float* x   = (const float*)d_in[0];   // (8,4096,768)
  const float* W1  = (const float*)d_in[1];   // (768,3072)
  const float* b1  = (const float*)d_in[2];   // (3072)
  const float* W2  = (const float*)d_in[3];   // (3072,768)
  const float* b2  = (const float*)d_in[4];   // (768)
  const float* g1  = (const float*)d_in[5];
  const float* be1 = (const float*)d_in[6];
  const float* g2  = (const float*)d_in[7];
  const float* be2 = (const float*)d_in[8];
  float* out = (float*)d_out;                 // fp32, also y2 scratch

  char* ws = (char*)d_ws;
  unsigned short* xb   = (unsigned short*)(ws + 0L);           //  50,331,648
  unsigned short* Bt1  = (unsigned short*)(ws + 50331648L);    //   1,572,864
  unsigned short* Au   = (unsigned short*)(ws + 51904512L);    //  18,874,368
  unsigned short* Av   = (unsigned short*)(ws + 70778880L);    //  18,874,368
  unsigned short* T    = (unsigned short*)(ws + 89653248L);    //  67,108,864 -> ends 156,762,112
  unsigned short* BtUV = (unsigned short*)(ws + 156762112L);   //  67,108,864 -> ends 223,870,976
  float*          u    = (float*)        (ws + 0L);            //  37,748,736 (aliases xb; dead after GEMM1)
  float*          v    = (float*)        (ws + 89653248L);     //  37,748,736 (aliases T; dead after transpose_T)
  unsigned short* H    = (unsigned short*)(ws + 0L);           // 201,326,592 (aliases all FFT buffers, dead by GEMM3)
  unsigned short* o1b  = (unsigned short*)(ws + 201326592L);   //  50,331,648 (overlaps BtUV tail, dead by combine_ln)
  unsigned short* W1t  = (unsigned short*)(ws + 251658240L);   //   4,718,592
  unsigned short* W2t  = (unsigned short*)(ws + 256376832L);   //   4,718,592
  // total ws needed: 261,095,424 bytes (~249 MiB)

  // --- prep ---
  f32_to_bf16_vec<<<24576, 256, 0, stream>>>(x, xb);
  fill_bt1<<<3072, 256, 0, stream>>>(Bt1);
  fill_auv<<<36864, 256, 0, stream>>>(Au, Av);                 // 2304*4096/256
  transpose_f32_to_bf16<<<dim3(96, 24), 256, 0, stream>>>(W1, W1t, 768, 3072);
  transpose_f32_to_bf16<<<dim3(24, 96), 256, 0, stream>>>(W2, W2t, 3072, 768);

  // --- GEMM1: T = xb @ Bt1^T (row-major, ld 1024); 128x4 = 512 blocks ---
  gemm256<0><<<512, 512, 0, stream>>>(
      xb, Bt1, nullptr, nullptr, 768, 768, 768, 0L, 0L, 999, 128, 4,
      nullptr, nullptr, T, nullptr, nullptr, 1024);

  // --- transpose T -> BtU/BtV ([b][d][s]) ---
  transpose_T<<<dim3(128, 32, 8), 256, 0, stream>>>(T, BtUV);

  // --- GEMM_uv fused (z<8: u = C_S @ Tc; z>=8: v = S_S @ Ts); 9x2x16 = 288 ---
  gemm256<1><<<288, 512, 0, stream>>>(
      Au, BtUV, Av, BtUV + 16777216L, 4096, 4096, 4096,
      512L * 4096L, 2304L * 512L, 8, 9, 2,
      u, v, nullptr, nullptr, nullptr, 512);

  // --- combine quadrants + x residual + LN1 -> out1 (bf16), fused ---
  combine_ln<<<dim3(2049, 8), 256, 0, stream>>>(u, v, x, g1, be1, o1b);

  // --- GEMM3: H = gelu(out1 @ W1 + b1); 128x12 = 1536 blocks ---
  gemm256<2><<<1536, 512, 0, stream>>>(
      o1b, W1t, nullptr, nullptr, 768, 768, 768, 0L, 0L, 999, 128, 12,
      nullptr, nullptr, H, b1, nullptr, 3072);

  // --- GEMM4: y2 = H @ W2 + b2 + out1 -> d_out; 128x3 = 384 blocks ---
  gemm256<3><<<384, 512, 0, stream>>>(
      H, W2t, nullptr, nullptr, 3072, 3072, 3072, 0L, 0L, 999, 128, 3,
      out, nullptr, nullptr, b2, o1b, 768);

  // --- LN2 in-place ---
  ln_row_f32<<<32768, 256, 0, stream>>>(out, g2, be2, out);
}

// Round 9
// 814.146 us; speedup vs baseline: 1.4985x; 1.0731x over previous
//
#include <hip/hip_runtime.h>
#include <cstdint>

// FNet block on MI355X.
//   attn = Re(FFT2(x)) via bf16 MFMA matmuls + real-input quadrant symmetry:
//     GEMM1: T[r][0:512]=Tc, T[r][512:1024]=Ts   (M=32768, N=1024, K=768)
//     transpose_T: BtU[b][d][s]=Tc[s,d], BtV[b][d][s]=Ts[s,d]
//     GEMM_uv (fused, z=0..15): u (cos) / v (sin), M=2304(pad), N=512, K=4096
//     combine_ln: quadrant-combine u+-v, +x residual, FUSED row-LayerNorm -> out1 bf16
//   GEMM3: H = gelu(out1 @ W1 + b1)       (M=32768, N=3072, K=768)  [fast tanh-gelu]
//   GEMM4: y2 = H @ W2 + b2 + out1        (M=32768, N=768, K=3072)
//   LN2 in-place on d_out.
//
// GEMM core (round 9): back to the m97/round-3 PROVEN structure for TLP —
// 128x128 tile, 4 waves, SINGLE 32 KiB LDS buffer, BK=64, 2 barriers/K-tile —
// so 3-4 blocks/CU co-reside and cross-block overlap hides barrier drains
// (the mechanism that round 4-8's 1-block/CU 256^2 core lacked). Upgrades vs
// round 3: T2 swizzle (same scolE/fxor math as verified 256^2 kernel; kills
// the 1.9e7 bank conflicts), BK=64 (half the barriers), gelu_fast, XCD-gather
// 1D grid + N-fastest decode (kept: cut FETCH 3x in round 8).

typedef __attribute__((ext_vector_type(8))) short short8;
typedef __attribute__((ext_vector_type(4))) float f32x4;

__device__ __forceinline__ unsigned short f2b(float f) {
  union { float f; uint32_t u; } c; c.f = f;
  uint32_t u = c.u;
  u += 0x7FFFu + ((u >> 16) & 1u);   // round-to-nearest-even
  return (unsigned short)(u >> 16);
}
__device__ __forceinline__ float b2f(unsigned short h) {
  union { uint32_t u; float f; } c; c.u = ((uint32_t)h) << 16;
  return c.f;
}

// fast GELU (tanh form), ~9 VALU: g = x*E/(E+1), E = exp(2*inner),
// inner = 0.79788456*x*(1 + 0.044715*x^2). max |err vs exact erf-gelu| ~3e-3.
__device__ __forceinline__ float gelu_fast(float x) {
  float x2 = x * x;
  float inner = x * fmaf(x2, 0.0356774081f, 0.7978845608f);
  float zz = fminf(inner * 2.885390082f, 80.0f);   // exp2 arg = 2*inner*log2(e)
  float E, r;
  asm("v_exp_f32 %0, %1" : "=v"(E) : "v"(zz));
  float den = E + 1.0f;
  asm("v_rcp_f32 %0, %1" : "=v"(r) : "v"(den));
  return x * E * r;
}

// ---------------------------------------------------------------------------
// Fill / convert kernels (unchanged, verified)
// ---------------------------------------------------------------------------

__global__ __launch_bounds__(256) void f32_to_bf16_vec(
    const float* __restrict__ in, unsigned short* __restrict__ out) {
  long i = (long)blockIdx.x * 256 + threadIdx.x;   // element-of-4 index
  float4 v = reinterpret_cast<const float4*>(in)[i];
  ushort4 o;
  o.x = f2b(v.x); o.y = f2b(v.y); o.z = f2b(v.z); o.w = f2b(v.w);
  reinterpret_cast<ushort4*>(out)[i] = o;
}

// Bt1: (1024 x 768). Row j<512: cos(2*pi*j*n/768); row j>=512: sin(2*pi*(j-512)*n/768).
__global__ __launch_bounds__(256) void fill_bt1(unsigned short* __restrict__ Bt1) {
  int i = blockIdx.x * 256 + threadIdx.x;          // < 1024*768
  int j = i / 768;
  int n = i - j * 768;
  int jj = j & 511;
  int m = (jj * n) % 768;
  float ang = (float)m * (6.283185307179586f / 768.0f);
  Bt1[i] = f2b((j < 512) ? cosf(ang) : sinf(ang));
}

// Au[k][s] = cos(2*pi*k*s/4096), Av[k][s] = sin(...), k=0..2303 (padded), s=0..4095.
__global__ __launch_bounds__(256) void fill_auv(
    unsigned short* __restrict__ Au, unsigned short* __restrict__ Av) {
  long i = (long)blockIdx.x * 256 + threadIdx.x;   // < 2304*4096
  int k = (int)(i >> 12);
  int s = (int)(i & 4095);
  int mm = (k * s) & 4095;
  float ang = (float)mm * (6.283185307179586f / 4096.0f);
  Au[i] = f2b(cosf(ang));
  Av[i] = f2b(sinf(ang));
}

// out[c][r] = bf16(in[r][c]); R,C multiples of 32  (for W1, W2)
__global__ __launch_bounds__(256) void transpose_f32_to_bf16(
    const float* __restrict__ in, unsigned short* __restrict__ out, int R, int C) {
  __shared__ float tile[32][33];
  const int c0 = blockIdx.x * 32;
  const int r0 = blockIdx.y * 32;
  const int tx = threadIdx.x & 31;
  const int ty = threadIdx.x >> 5;   // 0..7
#pragma unroll
  for (int i = ty; i < 32; i += 8)
    tile[i][tx] = in[(long)(r0 + i) * C + c0 + tx];
  __syncthreads();
#pragma unroll
  for (int i = ty; i < 32; i += 8)
    out[(long)(c0 + i) * R + r0 + tx] = f2b(tile[tx][i]);
}

// BtUV[(d<512?0:HALF) + (b*512 + (d&511))*4096 + s] = T[(b*4096+s)*1024 + d]
__global__ __launch_bounds__(256) void transpose_T(
    const unsigned short* __restrict__ T, unsigned short* __restrict__ BtUV) {
  __shared__ unsigned short tile[32][33];
  const int s0 = blockIdx.x * 32;
  const int d0 = blockIdx.y * 32;
  const int b  = blockIdx.z;
  const int tx = threadIdx.x & 31;
  const int ty = threadIdx.x >> 5;   // 0..7
  const unsigned short* Tb = T + ((long)b * 4096 + s0) * 1024 + d0;
#pragma unroll
  for (int i = ty; i < 32; i += 8)
    tile[i][tx] = Tb[(long)i * 1024 + tx];       // tile[s_local][d_local]
  __syncthreads();
#pragma unroll
  for (int i = ty; i < 32; i += 8) {
    const int d = d0 + i;
    const long off = (d < 512) ? 0L : 16777216L;
    BtUV[off + ((long)b * 512 + (d & 511)) * 4096 + s0 + tx] = tile[tx][i];
  }
}

// ---------------------------------------------------------------------------
// GEMM128: C = A (MxK row-major bf16) @ Bt^T (Bt NxK row-major bf16)
// 128x128 tile, BK=64, 256 threads (4 waves, 2x2), per-wave 64x64 output,
// acc[4][4]. Single 32 KiB LDS buffer, 2 syncthreads per K-tile (m97 form;
// relies on 3-4 blocks/CU for overlap). T2 swizzle on LDS reads with inverse
// pre-applied to the per-lane GLOBAL source column (gload_lds dest linear).
// 1D grid with XCD-gather remap (grid must be divisible by 8) + N-fastest:
// l = (p%8)*(total/8)+p/8; by = l%NY, bx = (l/NY)%NX, bz = l/(NY*NX).
// Epilogues: 0 = bf16 store (GEMM1->T); 1 = fp32 z-batched store, z>=zSplit
//            switches to (A2p,Bt2p,outF2) operand set (fused GEMM_u/GEMM_v);
//            2 = +bias, fast gelu, bf16 (GEMM3->H); 3 = +bias+bf16resid, fp32.
// M,N multiples of 128; K multiple of 64.
// ---------------------------------------------------------------------------

template <int EPI>
__global__ __launch_bounds__(256, 3) void gemm128(
    const unsigned short* __restrict__ A, const unsigned short* __restrict__ Bt,
    const unsigned short* __restrict__ A2p, const unsigned short* __restrict__ Bt2p,
    int K, int lda, int ldb, long bBatch, long oBatch, int zSplit,
    int NX, int NY,
    float* __restrict__ outF, float* __restrict__ outF2,
    unsigned short* __restrict__ outB,
    const float* __restrict__ bias, const unsigned short* __restrict__ residB,
    int ldOut) {
  __shared__ __align__(16) unsigned short As[128 * 64];   // 16 KB
  __shared__ __align__(16) unsigned short Bs[128 * 64];   // 16 KB

  const int tid = threadIdx.x;
  const int lane = tid & 63;
  const int wave = tid >> 6;         // 0..3
  const int wr = wave >> 1;          // 0..1
  const int wc = wave & 1;           // 0..1

  // ---- XCD-gather remap + N-fastest decode ----
  const int p = (int)blockIdx.x;
  const int l = (p & 7) * ((int)gridDim.x >> 3) + (p >> 3);
  const int by = l % NY;
  const int lx = l / NY;
  const int bx = lx % NX;
  int zz = lx / NX;

  const unsigned short* Ax = A;
  const unsigned short* Bx = Bt;
  float* oF = outF;
  if (EPI == 1 && zz >= zSplit) { Ax = A2p; Bx = Bt2p; oF = outF2; zz -= zSplit; }

  const unsigned short* Ab = Ax + (long)bx * 128 * lda;
  const unsigned short* Bb = Bx + (long)zz * bBatch + (long)by * 128 * ldb;

  const int NT = K >> 6;             // #K-tiles

  // Staging: linear LDS dest, T2 swizzle pre-applied to per-lane GLOBAL column.
  // Lane covers 16B at (row srow of its 8-row stripe, slot lane&7); global
  // source column = ((lane&7) ^ srow) * 8 elems so that the READ-side XOR
  // ((row&7)<<4 bytes) recovers linear data.
  const int srow = lane >> 3;                      // 0..7
  const int scolE = ((lane & 7) ^ srow) << 3;      // pre-swizzled col (elems)

  const int fr = lane & 15;          // frag row within 16
  const int fkB = (lane >> 4) << 4;  // byte k-offset within 32-k half (0,16,32,48)
  const int fxor = (lane & 7) << 4;  // T2 swizzle XOR (row&7 == lane&7 for frag rows)

  f32x4 acc[4][4] = {};

  for (int t = 0; t < NT; ++t) {
    // ---- stage tile t: 16 chunks of 8 rows; wave w does chunks i*4+w ----
#pragma unroll
    for (int i_ = 0; i_ < 4; ++i_) {
      const int chunk = i_ * 4 + wave;             // wave-uniform
      const int row = chunk * 8 + srow;
      __builtin_amdgcn_global_load_lds(
          (const __attribute__((address_space(1))) void*)(Ab + (long)row * lda + (long)t * 64 + scolE),
          (__attribute__((address_space(3))) void*)(As + chunk * 512), 16, 0, 0);
      __builtin_amdgcn_global_load_lds(
          (const __attribute__((address_space(1))) void*)(Bb + (long)row * ldb + (long)t * 64 + scolE),
          (__attribute__((address_space(3))) void*)(Bs + chunk * 512), 16, 0, 0);
    }
    __syncthreads();   // drains vmcnt (gload_lds) — data visible to all waves

    const char* Ap = reinterpret_cast<const char*>(As);
    const char* Bp = reinterpret_cast<const char*>(Bs);
#pragma unroll
    for (int ks = 0; ks < 2; ++ks) {
      short8 af[4], bf[4];
#pragma unroll
      for (int mf = 0; mf < 4; ++mf) {
        const int row = wr * 64 + mf * 16 + fr;
        af[mf] = *reinterpret_cast<const short8*>(Ap + ((row * 128 + ks * 64 + fkB) ^ fxor));
      }
#pragma unroll
      for (int nf = 0; nf < 4; ++nf) {
        const int row = wc * 64 + nf * 16 + fr;
        bf[nf] = *reinterpret_cast<const short8*>(Bp + ((row * 128 + ks * 64 + fkB) ^ fxor));
      }
#pragma unroll
      for (int mf = 0; mf < 4; ++mf)
#pragma unroll
        for (int nf = 0; nf < 4; ++nf)
          acc[mf][nf] = __builtin_amdgcn_mfma_f32_16x16x32_bf16(
              af[mf], bf[nf], acc[mf][nf], 0, 0, 0);
    }
    __syncthreads();   // all waves done reading before next stage overwrites
  }

  // Epilogue. C/D layout: col = lane&15, row = (lane>>4)*4 + reg  [m89/m91]
  const long rowBase = (long)bx * 128 + wr * 64 + ((lane >> 4) << 2);
  const int colBase = by * 128 + wc * 64 + (lane & 15);
#pragma unroll
  for (int mf = 0; mf < 4; ++mf) {
#pragma unroll
    for (int nf = 0; nf < 4; ++nf) {
      const int col = colBase + nf * 16;
#pragma unroll
      for (int i = 0; i < 4; ++i) {
        const long r = rowBase + mf * 16 + i;
        float vv = acc[mf][nf][i];
        if constexpr (EPI == 0) {
          outB[r * (long)ldOut + col] = f2b(vv);
        } else if constexpr (EPI == 1) {
          oF[(long)zz * oBatch + r * (long)ldOut + col] = vv;
        } else if constexpr (EPI == 2) {
          outB[r * (long)ldOut + col] = f2b(gelu_fast(vv + bias[col]));
        } else {
          const long idx = r * (long)ldOut + col;
          outF[idx] = vv + bias[col] + b2f(residB[idx]);
        }
      }
    }
  }
}

// ---------------------------------------------------------------------------
// combine_ln: quadrant combine + x residual + row LayerNorm, fused.
// Block (k,z) owns FULL rows k and 4096-k; writes out1 bf16 directly.
// ---------------------------------------------------------------------------
__global__ __launch_bounds__(256) void combine_ln(
    const float* __restrict__ u, const float* __restrict__ v,
    const float* __restrict__ x, const float* __restrict__ gamma,
    const float* __restrict__ beta, unsigned short* __restrict__ o1b) {
  const int k = blockIdx.x;            // 0..2048
  const int z = blockIdx.y;            // 0..7
  const long ub = ((long)z * 2304 + k) * 512;
  const long base = (long)z * 4096L * 768;
  const long rowA = base + (long)k * 768;
  const long rowB = base + (long)(4096 - k) * 768;
  const bool doRowB = (k != 0) && (k != 2048);
  const int t = threadIdx.x;

  float vA0[2], vA1[2], vB0[2], vB1[2];
  float sA = 0.f, qA = 0.f, sB = 0.f, qB = 0.f;
#pragma unroll
  for (int it = 0; it < 2; ++it) {
    const int d = t + it * 256;
    if (d <= 384) {
      const float uu = u[ub + d];
      const float vv = v[ub + d];
      const float a1 = uu - vv;
      const float a2 = uu + vv;
      const int dd = 768 - d;
      const bool colB = (d != 0) && (d != 384);
      float va = a1 + x[rowA + d];
      vA0[it] = va; sA += va; qA += va * va;
      if (colB) { float w = a2 + x[rowA + dd]; vA1[it] = w; sA += w; qA += w * w; }
      if (doRowB) {
        float wb = a2 + x[rowB + d];
        vB0[it] = wb; sB += wb; qB += wb * wb;
        if (colB) { float w2 = a1 + x[rowB + dd]; vB1[it] = w2; sB += w2; qB += w2 * w2; }
      }
    }
  }
#pragma unroll
  for (int off = 32; off > 0; off >>= 1) {
    sA += __shfl_down(sA, off, 64); qA += __shfl_down(qA, off, 64);
    sB += __shfl_down(sB, off, 64); qB += __shfl_down(qB, off, 64);
  }
  __shared__ float red[4][4];
  if ((t & 63) == 0) {
    red[t >> 6][0] = sA; red[t >> 6][1] = qA;
    red[t >> 6][2] = sB; red[t >> 6][3] = qB;
  }
  __syncthreads();
  const float SA = red[0][0] + red[1][0] + red[2][0] + red[3][0];
  const float QA = red[0][1] + red[1][1] + red[2][1] + red[3][1];
  const float SB = red[0][2] + red[1][2] + red[2][2] + red[3][2];
  const float QB = red[0][3] + red[1][3] + red[2][3] + red[3][3];
  const float muA = SA * (1.0f / 768.0f);
  const float rsA = rsqrtf(QA * (1.0f / 768.0f) - muA * muA + 1e-6f);
  const float muB = SB * (1.0f / 768.0f);
  const float rsB = rsqrtf(QB * (1.0f / 768.0f) - muB * muB + 1e-6f);

#pragma unroll
  for (int it = 0; it < 2; ++it) {
    const int d = t + it * 256;
    if (d <= 384) {
      const int dd = 768 - d;
      const bool colB = (d != 0) && (d != 384);
      const float g0 = gamma[d], b0 = beta[d];
      o1b[rowA + d] = f2b((vA0[it] - muA) * rsA * g0 + b0);
      if (colB) o1b[rowA + dd] = f2b((vA1[it] - muA) * rsA * gamma[dd] + beta[dd]);
      if (doRowB) {
        o1b[rowB + d] = f2b((vB0[it] - muB) * rsB * g0 + b0);
        if (colB) o1b[rowB + dd] = f2b((vB1[it] - muB) * rsB * gamma[dd] + beta[dd]);
      }
    }
  }
}

// ---------------------------------------------------------------------------
// Row LayerNorm over D=768 (fp32 in/out, used for LN2 in-place).
// ---------------------------------------------------------------------------
__global__ __launch_bounds__(256) void ln_row_f32(
    const float* __restrict__ in, const float* __restrict__ gamma,
    const float* __restrict__ beta, float* __restrict__ outF) {
  const long row = blockIdx.x;
  const float* p = in + row * 768;
  const int t = threadIdx.x;
  const float v0 = p[t], v1 = p[t + 256], v2 = p[t + 512];
  float s = v0 + v1 + v2;
  float q = v0 * v0 + v1 * v1 + v2 * v2;
#pragma unroll
  for (int off = 32; off > 0; off >>= 1) {
    s += __shfl_down(s, off, 64);
    q += __shfl_down(q, off, 64);
  }
  __shared__ float ss[4], sq[4];
  if ((t & 63) == 0) { ss[t >> 6] = s; sq[t >> 6] = q; }
  __syncthreads();
  const float S = ss[0] + ss[1] + ss[2] + ss[3];
  const float Q = sq[0] + sq[1] + sq[2] + sq[3];
  const float mu = S * (1.0f / 768.0f);
  const float var = Q * (1.0f / 768.0f) - mu * mu;
  const float rs = rsqrtf(var + 1e-6f);
  outF[row * 768 + t]       = (v0 - mu) * rs * gamma[t] + beta[t];
  outF[row * 768 + t + 256] = (v1 - mu) * rs * gamma[t + 256] + beta[t + 256];
  outF[row * 768 + t + 512] = (v2 - mu) * rs * gamma[t + 512] + beta[t + 512];
}

// ---------------------------------------------------------------------------

extern "C" void kernel_launch(void* const* d_in, const int* in_sizes, int n_in,
                              void* d_out, int out_size, void* d_ws, size_t ws_size,
                              hipStream_t stream) {
  const float* x   = (const float*)d_in[0];   // (8,4096,768)
  const float* W1  = (const float*)d_in[1];   // (768,3072)
  const float* b1  = (const float*)d_in[2];   // (3072)
  const float* W2  = (const float*)d_in[3];   // (3072,768)
  const float* b2  = (const float*)d_in[4];   // (768)
  const float* g1  = (const float*)d_in[5];
  const float* be1 = (const float*)d_in[6];
  const float* g2  = (const float*)d_in[7];
  const float* be2 = (const float*)d_in[8];
  float* out = (float*)d_out;                 // fp32, also y2 scratch

  char* ws = (char*)d_ws;
  unsigned short* xb   = (unsigned short*)(ws + 0L);           //  50,331,648
  unsigned short* Bt1  = (unsigned short*)(ws + 50331648L);    //   1,572,864
  unsigned short* Au   = (unsigned short*)(ws + 51904512L);    //  18,874,368
  unsigned short* Av   = (unsigned short*)(ws + 70778880L);    //  18,874,368
  unsigned short* T    = (unsigned short*)(ws + 89653248L);    //  67,108,864 -> ends 156,762,112
  unsigned short* BtUV = (unsigned short*)(ws + 156762112L);   //  67,108,864 -> ends 223,870,976
  float*          u    = (float*)        (ws + 0L);            //  37,748,736 (aliases xb; dead after GEMM1)
  float*          v    = (float*)        (ws + 89653248L);     //  37,748,736 (aliases T; dead after transpose_T)
  unsigned short* H    = (unsigned short*)(ws + 0L);           // 201,326,592 (aliases all FFT buffers, dead by GEMM3)
  unsigned short* o1b  = (unsigned short*)(ws + 201326592L);   //  50,331,648 (overlaps BtUV tail, dead by combine_ln)
  unsigned short* W1t  = (unsigned short*)(ws + 251658240L);   //   4,718,592
  unsigned short* W2t  = (unsigned short*)(ws + 256376832L);   //   4,718,592
  // total ws needed: 261,095,424 bytes (~249 MiB)

  // --- prep ---
  f32_to_bf16_vec<<<24576, 256, 0, stream>>>(x, xb);
  fill_bt1<<<3072, 256, 0, stream>>>(Bt1);
  fill_auv<<<36864, 256, 0, stream>>>(Au, Av);                 // 2304*4096/256
  transpose_f32_to_bf16<<<dim3(96, 24), 256, 0, stream>>>(W1, W1t, 768, 3072);
  transpose_f32_to_bf16<<<dim3(24, 96), 256, 0, stream>>>(W2, W2t, 3072, 768);

  // --- GEMM1: T = xb @ Bt1^T (row-major, ld 1024); 256x8 = 2048 blocks ---
  gemm128<0><<<2048, 256, 0, stream>>>(
      xb, Bt1, nullptr, nullptr, 768, 768, 768, 0L, 0L, 999, 256, 8,
      nullptr, nullptr, T, nullptr, nullptr, 1024);

  // --- transpose T -> BtU/BtV ([b][d][s]) ---
  transpose_T<<<dim3(128, 32, 8), 256, 0, stream>>>(T, BtUV);

  // --- GEMM_uv fused (z<8: u = C_S @ Tc; z>=8: v = S_S @ Ts); 18x4x16 = 1152 ---
  gemm128<1><<<1152, 256, 0, stream>>>(
      Au, BtUV, Av, BtUV + 16777216L, 4096, 4096, 4096,
      512L * 4096L, 2304L * 512L, 8, 18, 4,
      u, v, nullptr, nullptr, nullptr, 512);

  // --- combine quadrants + x residual + LN1 -> out1 (bf16), fused ---
  combine_ln<<<dim3(2049, 8), 256, 0, stream>>>(u, v, x, g1, be1, o1b);

  // --- GEMM3: H = gelu(out1 @ W1 + b1); 256x24 = 6144 blocks ---
  gemm128<2><<<6144, 256, 0, stream>>>(
      o1b, W1t, nullptr, nullptr, 768, 768, 768, 0L, 0L, 999, 256, 24,
      nullptr, nullptr, H, b1, nullptr, 3072);

  // --- GEMM4: y2 = H @ W2 + b2 + out1 -> d_out; 256x6 = 1536 blocks ---
  gemm128<3><<<1536, 256, 0, stream>>>(
      H, W2t, nullptr, nullptr, 3072, 3072, 3072, 0L, 0L, 999, 256, 6,
      out, nullptr, nullptr, b2, o1b, 768);

  // --- LN2 in-place ---
  ln_row_f32<<<32768, 256, 0, stream>>>(out, g2, be2, out);
}

// Round 10
// 722.294 us; speedup vs baseline: 1.6891x; 1.1272x over previous
//
#include <hip/hip_runtime.h>
#include <cstdint>

// FNet block on MI355X.
//   attn = Re(FFT2(x)) via bf16 MFMA matmuls + real-input quadrant symmetry:
//     GEMM1: T = X @ [C_D | S_D], epilogue packs DIRECTLY into BtU/BtV
//            ([b][d][s] layout) — no transpose_T pass (round-1-verified pattern)
//     GEMM_uv (fused, z=0..15): u (cos) / v (sin), M=2304(pad), N=512, K=4096,
//            stored bf16 in the freed T region
//     combine_ln: quadrant-combine u+-v (bf16), + xb residual (bf16),
//            fused row-LayerNorm -> out1 bf16
//   GEMM3: H = gelu(out1 @ W1 + b1)       (M=32768, N=3072, K=768)  [fast tanh-gelu]
//   GEMM4: y2 = H @ W2 + b2 + out1        (M=32768, N=768, K=3072)
//   LN2 in-place on d_out.
//
// GEMM core (unchanged from round 9, verified): 128x128 tile, BK=64, 4 waves,
// single 32 KiB LDS buffer, 2 barriers/K-tile, T2 swizzle (0 bank conflicts),
// gload_lds 16B staging, XCD-gather 1D grid + N-fastest decode.

typedef __attribute__((ext_vector_type(8))) short short8;
typedef __attribute__((ext_vector_type(4))) float f32x4;

__device__ __forceinline__ unsigned short f2b(float f) {
  union { float f; uint32_t u; } c; c.f = f;
  uint32_t u = c.u;
  u += 0x7FFFu + ((u >> 16) & 1u);   // round-to-nearest-even
  return (unsigned short)(u >> 16);
}
__device__ __forceinline__ float b2f(unsigned short h) {
  union { uint32_t u; float f; } c; c.u = ((uint32_t)h) << 16;
  return c.f;
}

// fast GELU (tanh form), ~9 VALU. max |err vs exact erf-gelu| ~3e-3.
__device__ __forceinline__ float gelu_fast(float x) {
  float x2 = x * x;
  float inner = x * fmaf(x2, 0.0356774081f, 0.7978845608f);
  float zz = fminf(inner * 2.885390082f, 80.0f);   // exp2 arg = 2*inner*log2(e)
  float E, r;
  asm("v_exp_f32 %0, %1" : "=v"(E) : "v"(zz));
  float den = E + 1.0f;
  asm("v_rcp_f32 %0, %1" : "=v"(r) : "v"(den));
  return x * E * r;
}

// ---------------------------------------------------------------------------
// Fill / convert kernels (unchanged, verified)
// ---------------------------------------------------------------------------

__global__ __launch_bounds__(256) void f32_to_bf16_vec(
    const float* __restrict__ in, unsigned short* __restrict__ out) {
  long i = (long)blockIdx.x * 256 + threadIdx.x;   // element-of-4 index
  float4 v = reinterpret_cast<const float4*>(in)[i];
  ushort4 o;
  o.x = f2b(v.x); o.y = f2b(v.y); o.z = f2b(v.z); o.w = f2b(v.w);
  reinterpret_cast<ushort4*>(out)[i] = o;
}

// Bt1: (1024 x 768). Row j<512: cos(2*pi*j*n/768); row j>=512: sin(2*pi*(j-512)*n/768).
__global__ __launch_bounds__(256) void fill_bt1(unsigned short* __restrict__ Bt1) {
  int i = blockIdx.x * 256 + threadIdx.x;          // < 1024*768
  int j = i / 768;
  int n = i - j * 768;
  int jj = j & 511;
  int m = (jj * n) % 768;
  float ang = (float)m * (6.283185307179586f / 768.0f);
  Bt1[i] = f2b((j < 512) ? cosf(ang) : sinf(ang));
}

// Au[k][s] = cos(2*pi*k*s/4096), Av[k][s] = sin(...), k=0..2303 (padded), s=0..4095.
__global__ __launch_bounds__(256) void fill_auv(
    unsigned short* __restrict__ Au, unsigned short* __restrict__ Av) {
  long i = (long)blockIdx.x * 256 + threadIdx.x;   // < 2304*4096
  int k = (int)(i >> 12);
  int s = (int)(i & 4095);
  int mm = (k * s) & 4095;
  float ang = (float)mm * (6.283185307179586f / 4096.0f);
  Au[i] = f2b(cosf(ang));
  Av[i] = f2b(sinf(ang));
}

// out[c][r] = bf16(in[r][c]); R,C multiples of 32  (for W1, W2)
__global__ __launch_bounds__(256) void transpose_f32_to_bf16(
    const float* __restrict__ in, unsigned short* __restrict__ out, int R, int C) {
  __shared__ float tile[32][33];
  const int c0 = blockIdx.x * 32;
  const int r0 = blockIdx.y * 32;
  const int tx = threadIdx.x & 31;
  const int ty = threadIdx.x >> 5;   // 0..7
#pragma unroll
  for (int i = ty; i < 32; i += 8)
    tile[i][tx] = in[(long)(r0 + i) * C + c0 + tx];
  __syncthreads();
#pragma unroll
  for (int i = ty; i < 32; i += 8)
    out[(long)(c0 + i) * R + r0 + tx] = f2b(tile[tx][i]);
}

// ---------------------------------------------------------------------------
// GEMM128: C = A (MxK row-major bf16) @ Bt^T (Bt NxK row-major bf16)
// 128x128 tile, BK=64, 256 threads (4 waves, 2x2), per-wave 64x64, acc[4][4].
// Single 32 KiB LDS buffer, 2 syncthreads/K-tile. T2 swizzle (reads XOR'd,
// inverse pre-applied to per-lane global source column; gload_lds dest linear).
// 1D grid, XCD-gather remap (grid % 8 == 0) + N-fastest decode:
//   l = (p%8)*(total/8)+p/8; by = l%NY, bx = (l/NY)%NX, bz = l/(NY*NX).
// Epilogues:
//   0 = pack into BtUV: col<512 -> U[b][col][s], col>=512 -> V[b][col-512][s]
//       (b = r>>12, s = r&4095; HALF = 16777216 elems)
//   1 = bf16 z-batched store; z>=zSplit switches operands (A2p,Bt2p,outB2)
//       (fused GEMM_u / GEMM_v, both bf16 out)
//   2 = +bias, fast gelu, bf16 (GEMM3->H)
//   3 = +bias +bf16 residual, fp32 (GEMM4->y2)
// M,N multiples of 128; K multiple of 64.
// ---------------------------------------------------------------------------

template <int EPI>
__global__ __launch_bounds__(256, 3) void gemm128(
    const unsigned short* __restrict__ A, const unsigned short* __restrict__ Bt,
    const unsigned short* __restrict__ A2p, const unsigned short* __restrict__ Bt2p,
    int K, int lda, int ldb, long bBatch, long oBatch, int zSplit,
    int NX, int NY,
    float* __restrict__ outF,
    unsigned short* __restrict__ outB, unsigned short* __restrict__ outB2,
    const float* __restrict__ bias, const unsigned short* __restrict__ residB,
    int ldOut) {
  __shared__ __align__(16) unsigned short As[128 * 64];   // 16 KB
  __shared__ __align__(16) unsigned short Bs[128 * 64];   // 16 KB

  const int tid = threadIdx.x;
  const int lane = tid & 63;
  const int wave = tid >> 6;         // 0..3
  const int wr = wave >> 1;          // 0..1
  const int wc = wave & 1;           // 0..1

  // ---- XCD-gather remap + N-fastest decode ----
  const int p = (int)blockIdx.x;
  const int l = (p & 7) * ((int)gridDim.x >> 3) + (p >> 3);
  const int by = l % NY;
  const int lx = l / NY;
  const int bx = lx % NX;
  int zz = lx / NX;

  const unsigned short* Ax = A;
  const unsigned short* Bx = Bt;
  unsigned short* oB = outB;
  if (EPI == 1 && zz >= zSplit) { Ax = A2p; Bx = Bt2p; oB = outB2; zz -= zSplit; }

  const unsigned short* Ab = Ax + (long)bx * 128 * lda;
  const unsigned short* Bb = Bx + (long)zz * bBatch + (long)by * 128 * ldb;

  const int NT = K >> 6;             // #K-tiles

  // Staging: linear LDS dest, T2 swizzle pre-applied to per-lane GLOBAL column.
  const int srow = lane >> 3;                      // 0..7
  const int scolE = ((lane & 7) ^ srow) << 3;      // pre-swizzled col (elems)

  const int fr = lane & 15;          // frag row within 16
  const int fkB = (lane >> 4) << 4;  // byte k-offset within 32-k half (0,16,32,48)
  const int fxor = (lane & 7) << 4;  // T2 swizzle XOR (row&7 == lane&7 for frag rows)

  f32x4 acc[4][4] = {};

  for (int t = 0; t < NT; ++t) {
    // ---- stage tile t: 16 chunks of 8 rows; wave w does chunks i*4+w ----
#pragma unroll
    for (int i_ = 0; i_ < 4; ++i_) {
      const int chunk = i_ * 4 + wave;             // wave-uniform
      const int row = chunk * 8 + srow;
      __builtin_amdgcn_global_load_lds(
          (const __attribute__((address_space(1))) void*)(Ab + (long)row * lda + (long)t * 64 + scolE),
          (__attribute__((address_space(3))) void*)(As + chunk * 512), 16, 0, 0);
      __builtin_amdgcn_global_load_lds(
          (const __attribute__((address_space(1))) void*)(Bb + (long)row * ldb + (long)t * 64 + scolE),
          (__attribute__((address_space(3))) void*)(Bs + chunk * 512), 16, 0, 0);
    }
    __syncthreads();   // drains vmcnt (gload_lds) — data visible to all waves

    const char* Ap = reinterpret_cast<const char*>(As);
    const char* Bp = reinterpret_cast<const char*>(Bs);
#pragma unroll
    for (int ks = 0; ks < 2; ++ks) {
      short8 af[4], bf[4];
#pragma unroll
      for (int mf = 0; mf < 4; ++mf) {
        const int row = wr * 64 + mf * 16 + fr;
        af[mf] = *reinterpret_cast<const short8*>(Ap + ((row * 128 + ks * 64 + fkB) ^ fxor));
      }
#pragma unroll
      for (int nf = 0; nf < 4; ++nf) {
        const int row = wc * 64 + nf * 16 + fr;
        bf[nf] = *reinterpret_cast<const short8*>(Bp + ((row * 128 + ks * 64 + fkB) ^ fxor));
      }
#pragma unroll
      for (int mf = 0; mf < 4; ++mf)
#pragma unroll
        for (int nf = 0; nf < 4; ++nf)
          acc[mf][nf] = __builtin_amdgcn_mfma_f32_16x16x32_bf16(
              af[mf], bf[nf], acc[mf][nf], 0, 0, 0);
    }
    __syncthreads();   // all waves done reading before next stage overwrites
  }

  // Epilogue. C/D layout: col = lane&15, row = (lane>>4)*4 + reg  [m89/m91]
  const long rowBase = (long)bx * 128 + wr * 64 + ((lane >> 4) << 2);
  const int colBase = by * 128 + wc * 64 + (lane & 15);
#pragma unroll
  for (int mf = 0; mf < 4; ++mf) {
#pragma unroll
    for (int nf = 0; nf < 4; ++nf) {
      const int col = colBase + nf * 16;
#pragma unroll
      for (int i = 0; i < 4; ++i) {
        const long r = rowBase + mf * 16 + i;
        float vv = acc[mf][nf][i];
        if constexpr (EPI == 0) {
          // pack T[r][col] -> BtUV: half = col>>9, d = col&511, b = r>>12, s = r&4095
          const long dst = (long)(col >> 9) * 16777216L +
                           ((((long)(r >> 12) << 9) + (col & 511)) << 12) + (r & 4095);
          outB[dst] = f2b(vv);
        } else if constexpr (EPI == 1) {
          oB[(long)zz * oBatch + r * (long)ldOut + col] = f2b(vv);
        } else if constexpr (EPI == 2) {
          outB[r * (long)ldOut + col] = f2b(gelu_fast(vv + bias[col]));
        } else {
          const long idx = r * (long)ldOut + col;
          outF[idx] = vv + bias[col] + b2f(residB[idx]);
        }
      }
    }
  }
}

// ---------------------------------------------------------------------------
// combine_ln: quadrant combine (bf16 u,v) + xb residual (bf16) + row LayerNorm.
// Block (k,z) owns FULL rows k and 4096-k; writes out1 bf16 directly.
// ---------------------------------------------------------------------------
__global__ __launch_bounds__(256) void combine_ln(
    const unsigned short* __restrict__ u, const unsigned short* __restrict__ v,
    const unsigned short* __restrict__ xb, const float* __restrict__ gamma,
    const float* __restrict__ beta, unsigned short* __restrict__ o1b) {
  const int k = blockIdx.x;            // 0..2048
  const int z = blockIdx.y;            // 0..7
  const long ub = ((long)z * 2304 + k) * 512;
  const long base = (long)z * 4096L * 768;
  const long rowA = base + (long)k * 768;
  const long rowB = base + (long)(4096 - k) * 768;
  const bool doRowB = (k != 0) && (k != 2048);
  const int t = threadIdx.x;

  float vA0[2], vA1[2], vB0[2], vB1[2];
  float sA = 0.f, qA = 0.f, sB = 0.f, qB = 0.f;
#pragma unroll
  for (int it = 0; it < 2; ++it) {
    const int d = t + it * 256;
    if (d <= 384) {
      const float uu = b2f(u[ub + d]);
      const float vv = b2f(v[ub + d]);
      const float a1 = uu - vv;
      const float a2 = uu + vv;
      const int dd = 768 - d;
      const bool colB = (d != 0) && (d != 384);
      float va = a1 + b2f(xb[rowA + d]);
      vA0[it] = va; sA += va; qA += va * va;
      if (colB) { float w = a2 + b2f(xb[rowA + dd]); vA1[it] = w; sA += w; qA += w * w; }
      if (doRowB) {
        float wb = a2 + b2f(xb[rowB + d]);
        vB0[it] = wb; sB += wb; qB += wb * wb;
        if (colB) { float w2 = a1 + b2f(xb[rowB + dd]); vB1[it] = w2; sB += w2; qB += w2 * w2; }
      }
    }
  }
#pragma unroll
  for (int off = 32; off > 0; off >>= 1) {
    sA += __shfl_down(sA, off, 64); qA += __shfl_down(qA, off, 64);
    sB += __shfl_down(sB, off, 64); qB += __shfl_down(qB, off, 64);
  }
  __shared__ float red[4][4];
  if ((t & 63) == 0) {
    red[t >> 6][0] = sA; red[t >> 6][1] = qA;
    red[t >> 6][2] = sB; red[t >> 6][3] = qB;
  }
  __syncthreads();
  const float SA = red[0][0] + red[1][0] + red[2][0] + red[3][0];
  const float QA = red[0][1] + red[1][1] + red[2][1] + red[3][1];
  const float SB = red[0][2] + red[1][2] + red[2][2] + red[3][2];
  const float QB = red[0][3] + red[1][3] + red[2][3] + red[3][3];
  const float muA = SA * (1.0f / 768.0f);
  const float rsA = rsqrtf(QA * (1.0f / 768.0f) - muA * muA + 1e-6f);
  const float muB = SB * (1.0f / 768.0f);
  const float rsB = rsqrtf(QB * (1.0f / 768.0f) - muB * muB + 1e-6f);

#pragma unroll
  for (int it = 0; it < 2; ++it) {
    const int d = t + it * 256;
    if (d <= 384) {
      const int dd = 768 - d;
      const bool colB = (d != 0) && (d != 384);
      const float g0 = gamma[d], b0 = beta[d];
      o1b[rowA + d] = f2b((vA0[it] - muA) * rsA * g0 + b0);
      if (colB) o1b[rowA + dd] = f2b((vA1[it] - muA) * rsA * gamma[dd] + beta[dd]);
      if (doRowB) {
        o1b[rowB + d] = f2b((vB0[it] - muB) * rsB * g0 + b0);
        if (colB) o1b[rowB + dd] = f2b((vB1[it] - muB) * rsB * gamma[dd] + beta[dd]);
      }
    }
  }
}

// ---------------------------------------------------------------------------
// Row LayerNorm over D=768 (fp32 in/out, used for LN2 in-place).
// ---------------------------------------------------------------------------
__global__ __launch_bounds__(256) void ln_row_f32(
    const float* __restrict__ in, const float* __restrict__ gamma,
    const float* __restrict__ beta, float* __restrict__ outF) {
  const long row = blockIdx.x;
  const float* p = in + row * 768;
  const int t = threadIdx.x;
  const float v0 = p[t], v1 = p[t + 256], v2 = p[t + 512];
  float s = v0 + v1 + v2;
  float q = v0 * v0 + v1 * v1 + v2 * v2;
#pragma unroll
  for (int off = 32; off > 0; off >>= 1) {
    s += __shfl_down(s, off, 64);
    q += __shfl_down(q, off, 64);
  }
  __shared__ float ss[4], sq[4];
  if ((t & 63) == 0) { ss[t >> 6] = s; sq[t >> 6] = q; }
  __syncthreads();
  const float S = ss[0] + ss[1] + ss[2] + ss[3];
  const float Q = sq[0] + sq[1] + sq[2] + sq[3];
  const float mu = S * (1.0f / 768.0f);
  const float var = Q * (1.0f / 768.0f) - mu * mu;
  const float rs = rsqrtf(var + 1e-6f);
  outF[row * 768 + t]       = (v0 - mu) * rs * gamma[t] + beta[t];
  outF[row * 768 + t + 256] = (v1 - mu) * rs * gamma[t + 256] + beta[t + 256];
  outF[row * 768 + t + 512] = (v2 - mu) * rs * gamma[t + 512] + beta[t + 512];
}

// ---------------------------------------------------------------------------

extern "C" void kernel_launch(void* const* d_in, const int* in_sizes, int n_in,
                              void* d_out, int out_size, void* d_ws, size_t ws_size,
                              hipStream_t stream) {
  const float* x   = (const float*)d_in[0];   // (8,4096,768)
  const float* W1  = (const float*)d_in[1];   // (768,3072)
  const float* b1  = (const float*)d_in[2];   // (3072)
  const float* W2  = (const float*)d_in[3];   // (3072,768)
  const float* b2  = (const float*)d_in[4];   // (768)
  const float* g1  = (const float*)d_in[5];
  const float* be1 = (const float*)d_in[6];
  const float* g2  = (const float*)d_in[7];
  const float* be2 = (const float*)d_in[8];
  float* out = (float*)d_out;                 // fp32, also y2 scratch

  char* ws = (char*)d_ws;
  unsigned short* xb   = (unsigned short*)(ws + 0L);           //  50,331,648 (live until combine_ln)
  unsigned short* Bt1  = (unsigned short*)(ws + 50331648L);    //   1,572,864
  unsigned short* Au   = (unsigned short*)(ws + 51904512L);    //  18,874,368
  unsigned short* Av   = (unsigned short*)(ws + 70778880L);    //  18,874,368
  unsigned short* u_b  = (unsigned short*)(ws + 89653248L);    //  18,874,368 (freed T region)
  unsigned short* v_b  = (unsigned short*)(ws + 108527616L);   //  18,874,368 -> ends 127,401,984
  unsigned short* BtUV = (unsigned short*)(ws + 156762112L);   //  67,108,864 -> ends 223,870,976
  unsigned short* H    = (unsigned short*)(ws + 0L);           // 201,326,592 (aliases xb/Au/Av/u/v/BtUV-head; all dead by GEMM3)
  unsigned short* o1b  = (unsigned short*)(ws + 201326592L);   //  50,331,648 (overlaps BtUV tail, dead by combine_ln)
  unsigned short* W1t  = (unsigned short*)(ws + 251658240L);   //   4,718,592
  unsigned short* W2t  = (unsigned short*)(ws + 256376832L);   //   4,718,592
  // total ws needed: 261,095,424 bytes (~249 MiB)

  // --- prep ---
  f32_to_bf16_vec<<<24576, 256, 0, stream>>>(x, xb);
  fill_bt1<<<3072, 256, 0, stream>>>(Bt1);
  fill_auv<<<36864, 256, 0, stream>>>(Au, Av);                 // 2304*4096/256
  transpose_f32_to_bf16<<<dim3(96, 24), 256, 0, stream>>>(W1, W1t, 768, 3072);
  transpose_f32_to_bf16<<<dim3(24, 96), 256, 0, stream>>>(W2, W2t, 3072, 768);

  // --- GEMM1: pack X @ [C_D|S_D] directly into BtU/BtV; 256x8 = 2048 blocks ---
  gemm128<0><<<2048, 256, 0, stream>>>(
      xb, Bt1, nullptr, nullptr, 768, 768, 768, 0L, 0L, 999, 256, 8,
      nullptr, BtUV, nullptr, nullptr, nullptr, 0);

  // --- GEMM_uv fused (z<8: u = C_S @ Tc -> u_b; z>=8: v = S_S @ Ts -> v_b);
  //     18x4x16 = 1152 blocks, bf16 outputs ---
  gemm128<1><<<1152, 256, 0, stream>>>(
      Au, BtUV, Av, BtUV + 16777216L, 4096, 4096, 4096,
      512L * 4096L, 2304L * 512L, 8, 18, 4,
      nullptr, u_b, v_b, nullptr, nullptr, 512);

  // --- combine quadrants + xb residual + LN1 -> out1 (bf16), fused ---
  combine_ln<<<dim3(2049, 8), 256, 0, stream>>>(u_b, v_b, xb, g1, be1, o1b);

  // --- GEMM3: H = gelu(out1 @ W1 + b1); 256x24 = 6144 blocks ---
  gemm128<2><<<6144, 256, 0, stream>>>(
      o1b, W1t, nullptr, nullptr, 768, 768, 768, 0L, 0L, 999, 256, 24,
      nullptr, H, nullptr, b1, nullptr, 3072);

  // --- GEMM4: y2 = H @ W2 + b2 + out1 -> d_out; 256x6 = 1536 blocks ---
  gemm128<3><<<1536, 256, 0, stream>>>(
      H, W2t, nullptr, nullptr, 3072, 3072, 3072, 0L, 0L, 999, 256, 6,
      out, nullptr, nullptr, b2, o1b, 768);

  // --- LN2 in-place ---
  ln_row_f32<<<32768, 256, 0, stream>>>(out, g2, be2, out);
}

// Round 12
// 666.884 us; speedup vs baseline: 1.8294x; 1.0831x over previous
//
#include <hip/hip_runtime.h>
#include <cstdint>

// FNet block on MI355X.
//   attn = Re(FFT2(x)) via bf16 MFMA matmuls + real-input quadrant symmetry:
//     GEMM1: T = X @ [C_D | S_D], epilogue packs DIRECTLY into BtU/BtV [b][d][s]
//     fold_s: K-axis symmetry fold (cos even / sin odd about s=2048):
//             Uf[s']=U[s']+U[4096-s'] (s'=1..2047), Uf[0]=U[0], Uf[2048]=U[2048],
//             Vf[s']=V[s']-V[4096-s'], zeros at s'=0,2048; pad to K=2112.
//             ROW SPACE IS 4096 ROWS (8 batches x 512 d) — round-11 bug was
//             launching 8192 blocks, which overwrote the Vf region.
//     GEMM_uv (fused, z=0..15): u (cos) / v (sin), M=2304(pad), N=512, K=2112
//     combine_ln: quadrant-combine u+-v (bf16), + xb residual (bf16),
//            fused row-LayerNorm -> out1 bf16
//   GEMM3: H = gelu(out1 @ W1 + b1)       (M=32768, N=3072, K=768)  [fast tanh-gelu]
//   GEMM4: y2 = H @ W2 + b2 + out1        (M=32768, N=768, K=3072)
//   LN2 in-place on d_out.
//
// GEMM core (unchanged from round 9/10, verified): 128x128 tile, BK=64, 4 waves,
// single 32 KiB LDS buffer, 2 barriers/K-tile, T2 swizzle (0 bank conflicts),
// gload_lds 16B staging, XCD-gather 1D grid + N-fastest decode.

typedef __attribute__((ext_vector_type(8))) short short8;
typedef __attribute__((ext_vector_type(4))) float f32x4;

__device__ __forceinline__ unsigned short f2b(float f) {
  union { float f; uint32_t u; } c; c.f = f;
  uint32_t u = c.u;
  u += 0x7FFFu + ((u >> 16) & 1u);   // round-to-nearest-even
  return (unsigned short)(u >> 16);
}
__device__ __forceinline__ float b2f(unsigned short h) {
  union { uint32_t u; float f; } c; c.u = ((uint32_t)h) << 16;
  return c.f;
}

// fast GELU (tanh form), ~9 VALU. max |err vs exact erf-gelu| ~3e-3.
__device__ __forceinline__ float gelu_fast(float x) {
  float x2 = x * x;
  float inner = x * fmaf(x2, 0.0356774081f, 0.7978845608f);
  float zz = fminf(inner * 2.885390082f, 80.0f);   // exp2 arg = 2*inner*log2(e)
  float E, r;
  asm("v_exp_f32 %0, %1" : "=v"(E) : "v"(zz));
  float den = E + 1.0f;
  asm("v_rcp_f32 %0, %1" : "=v"(r) : "v"(den));
  return x * E * r;
}

// ---------------------------------------------------------------------------
// Fill / convert kernels
// ---------------------------------------------------------------------------

__global__ __launch_bounds__(256) void f32_to_bf16_vec(
    const float* __restrict__ in, unsigned short* __restrict__ out) {
  long i = (long)blockIdx.x * 256 + threadIdx.x;   // element-of-4 index
  float4 v = reinterpret_cast<const float4*>(in)[i];
  ushort4 o;
  o.x = f2b(v.x); o.y = f2b(v.y); o.z = f2b(v.z); o.w = f2b(v.w);
  reinterpret_cast<ushort4*>(out)[i] = o;
}

// Bt1: (1024 x 768). Row j<512: cos(2*pi*j*n/768); row j>=512: sin(2*pi*(j-512)*n/768).
__global__ __launch_bounds__(256) void fill_bt1(unsigned short* __restrict__ Bt1) {
  int i = blockIdx.x * 256 + threadIdx.x;          // < 1024*768
  int j = i / 768;
  int n = i - j * 768;
  int jj = j & 511;
  int m = (jj * n) % 768;
  float ang = (float)m * (6.283185307179586f / 768.0f);
  Bt1[i] = f2b((j < 512) ? cosf(ang) : sinf(ang));
}

// Au[k][s'] = cos(2*pi*k*s'/4096), Av[k][s'] = sin(...), k=0..2303, s'=0..2111.
// (s' >= 2049 multiplies zero-padded data; any finite value is safe.)
__global__ __launch_bounds__(256) void fill_auv(
    unsigned short* __restrict__ Au, unsigned short* __restrict__ Av) {
  long i = (long)blockIdx.x * 256 + threadIdx.x;   // < 2304*2112
  if (i >= 2304L * 2112L) return;
  int k = (int)(i / 2112);
  int s = (int)(i - (long)k * 2112);
  int mm = (k * s) & 4095;
  float ang = (float)mm * (6.283185307179586f / 4096.0f);
  Au[i] = f2b(cosf(ang));
  Av[i] = f2b(sinf(ang));
}

// out[c][r] = bf16(in[r][c]); R,C multiples of 32  (for W1, W2)
__global__ __launch_bounds__(256) void transpose_f32_to_bf16(
    const float* __restrict__ in, unsigned short* __restrict__ out, int R, int C) {
  __shared__ float tile[32][33];
  const int c0 = blockIdx.x * 32;
  const int r0 = blockIdx.y * 32;
  const int tx = threadIdx.x & 31;
  const int ty = threadIdx.x >> 5;   // 0..7
#pragma unroll
  for (int i = ty; i < 32; i += 8)
    tile[i][tx] = in[(long)(r0 + i) * C + c0 + tx];
  __syncthreads();
#pragma unroll
  for (int i = ty; i < 32; i += 8)
    out[(long)(c0 + i) * R + r0 + tx] = f2b(tile[tx][i]);
}

// ---------------------------------------------------------------------------
// fold_s: per (b,d) row, fold s-axis symmetry of the length-4096 DFT.
//   Uf[s'] = U[s'] + U[4096-s'] (1<=s'<=2047); Uf[0]=U[0]; Uf[2048]=U[2048];
//   Vf[s'] = V[s'] - V[4096-s'] (1<=s'<=2047); Vf[0]=Vf[2048]=0;  pad->2112 zeros.
// EXACTLY 4096 rows (8 batches x 512 d). One block per row.
// ---------------------------------------------------------------------------
__global__ __launch_bounds__(256) void fold_s(
    const unsigned short* __restrict__ BtUV, unsigned short* __restrict__ BtUVf) {
  const long row = blockIdx.x;          // 0..4095
  const unsigned short* U = BtUV + (row << 12);
  const unsigned short* V = BtUV + 16777216L + (row << 12);
  unsigned short* Uf = BtUVf + row * 2112;
  unsigned short* Vf = BtUVf + 8650752L + row * 2112;
  for (int s = threadIdx.x; s < 2112; s += 256) {
    float uo, vo;
    if (s == 0)        { uo = b2f(U[0]);    vo = 0.f; }
    else if (s < 2048) { uo = b2f(U[s]) + b2f(U[4096 - s]);
                         vo = b2f(V[s]) - b2f(V[4096 - s]); }
    else if (s == 2048){ uo = b2f(U[2048]); vo = 0.f; }
    else               { uo = 0.f;          vo = 0.f; }
    Uf[s] = f2b(uo);
    Vf[s] = f2b(vo);
  }
}

// ---------------------------------------------------------------------------
// GEMM128: C = A (MxK row-major bf16) @ Bt^T (Bt NxK row-major bf16)
// 128x128 tile, BK=64, 256 threads (4 waves, 2x2), per-wave 64x64, acc[4][4].
// Single 32 KiB LDS buffer, 2 syncthreads/K-tile. T2 swizzle (reads XOR'd,
// inverse pre-applied to per-lane global source column; gload_lds dest linear).
// 1D grid, XCD-gather remap (grid % 8 == 0) + N-fastest decode:
//   l = (p%8)*(total/8)+p/8; by = l%NY, bx = (l/NY)%NX, bz = l/(NY*NX).
// Epilogues:
//   0 = pack into BtUV: col<512 -> U[b][col][s], col>=512 -> V[b][col-512][s]
//   1 = bf16 z-batched store; z>=zSplit switches operands (A2p,Bt2p,outB2)
//   2 = +bias, fast gelu, bf16 (GEMM3->H)
//   3 = +bias +bf16 residual, fp32 (GEMM4->y2)
// M,N multiples of 128; K multiple of 64.
// ---------------------------------------------------------------------------

template <int EPI>
__global__ __launch_bounds__(256, 3) void gemm128(
    const unsigned short* __restrict__ A, const unsigned short* __restrict__ Bt,
    const unsigned short* __restrict__ A2p, const unsigned short* __restrict__ Bt2p,
    int K, int lda, int ldb, long bBatch, long oBatch, int zSplit,
    int NX, int NY,
    float* __restrict__ outF,
    unsigned short* __restrict__ outB, unsigned short* __restrict__ outB2,
    const float* __restrict__ bias, const unsigned short* __restrict__ residB,
    int ldOut) {
  __shared__ __align__(16) unsigned short As[128 * 64];   // 16 KB
  __shared__ __align__(16) unsigned short Bs[128 * 64];   // 16 KB

  const int tid = threadIdx.x;
  const int lane = tid & 63;
  const int wave = tid >> 6;         // 0..3
  const int wr = wave >> 1;          // 0..1
  const int wc = wave & 1;           // 0..1

  // ---- XCD-gather remap + N-fastest decode ----
  const int p = (int)blockIdx.x;
  const int l = (p & 7) * ((int)gridDim.x >> 3) + (p >> 3);
  const int by = l % NY;
  const int lx = l / NY;
  const int bx = lx % NX;
  int zz = lx / NX;

  const unsigned short* Ax = A;
  const unsigned short* Bx = Bt;
  unsigned short* oB = outB;
  if (EPI == 1 && zz >= zSplit) { Ax = A2p; Bx = Bt2p; oB = outB2; zz -= zSplit; }

  const unsigned short* Ab = Ax + (long)bx * 128 * lda;
  const unsigned short* Bb = Bx + (long)zz * bBatch + (long)by * 128 * ldb;

  const int NT = K >> 6;             // #K-tiles

  // Staging: linear LDS dest, T2 swizzle pre-applied to per-lane GLOBAL column.
  const int srow = lane >> 3;                      // 0..7
  const int scolE = ((lane & 7) ^ srow) << 3;      // pre-swizzled col (elems)

  const int fr = lane & 15;          // frag row within 16
  const int fkB = (lane >> 4) << 4;  // byte k-offset within 32-k half (0,16,32,48)
  const int fxor = (lane & 7) << 4;  // T2 swizzle XOR (row&7 == lane&7 for frag rows)

  f32x4 acc[4][4] = {};

  for (int t = 0; t < NT; ++t) {
    // ---- stage tile t: 16 chunks of 8 rows; wave w does chunks i*4+w ----
#pragma unroll
    for (int i_ = 0; i_ < 4; ++i_) {
      const int chunk = i_ * 4 + wave;             // wave-uniform
      const int row = chunk * 8 + srow;
      __builtin_amdgcn_global_load_lds(
          (const __attribute__((address_space(1))) void*)(Ab + (long)row * lda + (long)t * 64 + scolE),
          (__attribute__((address_space(3))) void*)(As + chunk * 512), 16, 0, 0);
      __builtin_amdgcn_global_load_lds(
          (const __attribute__((address_space(1))) void*)(Bb + (long)row * ldb + (long)t * 64 + scolE),
          (__attribute__((address_space(3))) void*)(Bs + chunk * 512), 16, 0, 0);
    }
    __syncthreads();   // drains vmcnt (gload_lds) — data visible to all waves

    const char* Ap = reinterpret_cast<const char*>(As);
    const char* Bp = reinterpret_cast<const char*>(Bs);
#pragma unroll
    for (int ks = 0; ks < 2; ++ks) {
      short8 af[4], bf[4];
#pragma unroll
      for (int mf = 0; mf < 4; ++mf) {
        const int row = wr * 64 + mf * 16 + fr;
        af[mf] = *reinterpret_cast<const short8*>(Ap + ((row * 128 + ks * 64 + fkB) ^ fxor));
      }
#pragma unroll
      for (int nf = 0; nf < 4; ++nf) {
        const int row = wc * 64 + nf * 16 + fr;
        bf[nf] = *reinterpret_cast<const short8*>(Bp + ((row * 128 + ks * 64 + fkB) ^ fxor));
      }
#pragma unroll
      for (int mf = 0; mf < 4; ++mf)
#pragma unroll
        for (int nf = 0; nf < 4; ++nf)
          acc[mf][nf] = __builtin_amdgcn_mfma_f32_16x16x32_bf16(
              af[mf], bf[nf], acc[mf][nf], 0, 0, 0);
    }
    __syncthreads();   // all waves done reading before next stage overwrites
  }

  // Epilogue. C/D layout: col = lane&15, row = (lane>>4)*4 + reg  [m89/m91]
  const long rowBase = (long)bx * 128 + wr * 64 + ((lane >> 4) << 2);
  const int colBase = by * 128 + wc * 64 + (lane & 15);
#pragma unroll
  for (int mf = 0; mf < 4; ++mf) {
#pragma unroll
    for (int nf = 0; nf < 4; ++nf) {
      const int col = colBase + nf * 16;
#pragma unroll
      for (int i = 0; i < 4; ++i) {
        const long r = rowBase + mf * 16 + i;
        float vv = acc[mf][nf][i];
        if constexpr (EPI == 0) {
          // pack T[r][col] -> BtUV: half = col>>9, d = col&511, b = r>>12, s = r&4095
          const long dst = (long)(col >> 9) * 16777216L +
                           ((((long)(r >> 12) << 9) + (col & 511)) << 12) + (r & 4095);
          outB[dst] = f2b(vv);
        } else if constexpr (EPI == 1) {
          oB[(long)zz * oBatch + r * (long)ldOut + col] = f2b(vv);
        } else if constexpr (EPI == 2) {
          outB[r * (long)ldOut + col] = f2b(gelu_fast(vv + bias[col]));
        } else {
          const long idx = r * (long)ldOut + col;
          outF[idx] = vv + bias[col] + b2f(residB[idx]);
        }
      }
    }
  }
}

// ---------------------------------------------------------------------------
// combine_ln: quadrant combine (bf16 u,v) + xb residual (bf16) + row LayerNorm.
// Block (k,z) owns FULL rows k and 4096-k; writes out1 bf16 directly.
// ---------------------------------------------------------------------------
__global__ __launch_bounds__(256) void combine_ln(
    const unsigned short* __restrict__ u, const unsigned short* __restrict__ v,
    const unsigned short* __restrict__ xb, const float* __restrict__ gamma,
    const float* __restrict__ beta, unsigned short* __restrict__ o1b) {
  const int k = blockIdx.x;            // 0..2048
  const int z = blockIdx.y;            // 0..7
  const long ub = ((long)z * 2304 + k) * 512;
  const long base = (long)z * 4096L * 768;
  const long rowA = base + (long)k * 768;
  const long rowB = base + (long)(4096 - k) * 768;
  const bool doRowB = (k != 0) && (k != 2048);
  const int t = threadIdx.x;

  float vA0[2], vA1[2], vB0[2], vB1[2];
  float sA = 0.f, qA = 0.f, sB = 0.f, qB = 0.f;
#pragma unroll
  for (int it = 0; it < 2; ++it) {
    const int d = t + it * 256;
    if (d <= 384) {
      const float uu = b2f(u[ub + d]);
      const float vv = b2f(v[ub + d]);
      const float a1 = uu - vv;
      const float a2 = uu + vv;
      const int dd = 768 - d;
      const bool colB = (d != 0) && (d != 384);
      float va = a1 + b2f(xb[rowA + d]);
      vA0[it] = va; sA += va; qA += va * va;
      if (colB) { float w = a2 + b2f(xb[rowA + dd]); vA1[it] = w; sA += w; qA += w * w; }
      if (doRowB) {
        float wb = a2 + b2f(xb[rowB + d]);
        vB0[it] = wb; sB += wb; qB += wb * wb;
        if (colB) { float w2 = a1 + b2f(xb[rowB + dd]); vB1[it] = w2; sB += w2; qB += w2 * w2; }
      }
    }
  }
#pragma unroll
  for (int off = 32; off > 0; off >>= 1) {
    sA += __shfl_down(sA, off, 64); qA += __shfl_down(qA, off, 64);
    sB += __shfl_down(sB, off, 64); qB += __shfl_down(qB, off, 64);
  }
  __shared__ float red[4][4];
  if ((t & 63) == 0) {
    red[t >> 6][0] = sA; red[t >> 6][1] = qA;
    red[t >> 6][2] = sB; red[t >> 6][3] = qB;
  }
  __syncthreads();
  const float SA = red[0][0] + red[1][0] + red[2][0] + red[3][0];
  const float QA = red[0][1] + red[1][1] + red[2][1] + red[3][1];
  const float SB = red[0][2] + red[1][2] + red[2][2] + red[3][2];
  const float QB = red[0][3] + red[1][3] + red[2][3] + red[3][3];
  const float muA = SA * (1.0f / 768.0f);
  const float rsA = rsqrtf(QA * (1.0f / 768.0f) - muA * muA + 1e-6f);
  const float muB = SB * (1.0f / 768.0f);
  const float rsB = rsqrtf(QB * (1.0f / 768.0f) - muB * muB + 1e-6f);

#pragma unroll
  for (int it = 0; it < 2; ++it) {
    const int d = t + it * 256;
    if (d <= 384) {
      const int dd = 768 - d;
      const bool colB = (d != 0) && (d != 384);
      const float g0 = gamma[d], b0 = beta[d];
      o1b[rowA + d] = f2b((vA0[it] - muA) * rsA * g0 + b0);
      if (colB) o1b[rowA + dd] = f2b((vA1[it] - muA) * rsA * gamma[dd] + beta[dd]);
      if (doRowB) {
        o1b[rowB + d] = f2b((vB0[it] - muB) * rsB * g0 + b0);
        if (colB) o1b[rowB + dd] = f2b((vB1[it] - muB) * rsB * gamma[dd] + beta[dd]);
      }
    }
  }
}

// ---------------------------------------------------------------------------
// Row LayerNorm over D=768 (fp32 in/out, used for LN2 in-place).
// ---------------------------------------------------------------------------
__global__ __launch_bounds__(256) void ln_row_f32(
    const float* __restrict__ in, const float* __restrict__ gamma,
    const float* __restrict__ beta, float* __restrict__ outF) {
  const long row = blockIdx.x;
  const float* p = in + row * 768;
  const int t = threadIdx.x;
  const float v0 = p[t], v1 = p[t + 256], v2 = p[t + 512];
  float s = v0 + v1 + v2;
  float q = v0 * v0 + v1 * v1 + v2 * v2;
#pragma unroll
  for (int off = 32; off > 0; off >>= 1) {
    s += __shfl_down(s, off, 64);
    q += __shfl_down(q, off, 64);
  }
  __shared__ float ss[4], sq[4];
  if ((t & 63) == 0) { ss[t >> 6] = s; sq[t >> 6] = q; }
  __syncthreads();
  const float S = ss[0] + ss[1] + ss[2] + ss[3];
  const float Q = sq[0] + sq[1] + sq[2] + sq[3];
  const float mu = S * (1.0f / 768.0f);
  const float var = Q * (1.0f / 768.0f) - mu * mu;
  const float rs = rsqrtf(var + 1e-6f);
  outF[row * 768 + t]       = (v0 - mu) * rs * gamma[t] + beta[t];
  outF[row * 768 + t + 256] = (v1 - mu) * rs * gamma[t + 256] + beta[t + 256];
  outF[row * 768 + t + 512] = (v2 - mu) * rs * gamma[t + 512] + beta[t + 512];
}

// ---------------------------------------------------------------------------

extern "C" void kernel_launch(void* const* d_in, const int* in_sizes, int n_in,
                              void* d_out, int out_size, void* d_ws, size_t ws_size,
                              hipStream_t stream) {
  const float* x   = (const float*)d_in[0];   // (8,4096,768)
  const float* W1  = (const float*)d_in[1];   // (768,3072)
  const float* b1  = (const float*)d_in[2];   // (3072)
  const float* W2  = (const float*)d_in[3];   // (3072,768)
  const float* b2  = (const float*)d_in[4];   // (768)
  const float* g1  = (const float*)d_in[5];
  const float* be1 = (const float*)d_in[6];
  const float* g2  = (const float*)d_in[7];
  const float* be2 = (const float*)d_in[8];
  float* out = (float*)d_out;                 // fp32, also y2 scratch

  char* ws = (char*)d_ws;
  unsigned short* xb    = (unsigned short*)(ws + 0L);           //  50,331,648 (live until combine_ln)
  unsigned short* Bt1   = (unsigned short*)(ws + 50331648L);    //   1,572,864
  unsigned short* Au    = (unsigned short*)(ws + 51904512L);    //   9,732,096 (2304x2112)
  unsigned short* Av    = (unsigned short*)(ws + 61636608L);    //   9,732,096
  unsigned short* u_b   = (unsigned short*)(ws + 71368704L);    //  18,874,368
  unsigned short* v_b   = (unsigned short*)(ws + 90243072L);    //  18,874,368 -> ends 109,117,440
  unsigned short* BtUVf = (unsigned short*)(ws + 109117440L);   //  34,603,008 -> ends 143,720,448
  unsigned short* BtUV  = (unsigned short*)(ws + 156762112L);   //  67,108,864 -> ends 223,870,976 (dead after fold_s)
  unsigned short* H     = (unsigned short*)(ws + 0L);           // 201,326,592 (aliases everything below o1b; all dead by GEMM3)
  unsigned short* o1b   = (unsigned short*)(ws + 201326592L);   //  50,331,648 (overlaps dead BtUV tail)
  unsigned short* W1t   = (unsigned short*)(ws + 251658240L);   //   4,718,592
  unsigned short* W2t   = (unsigned short*)(ws + 256376832L);   //   4,718,592
  // total ws needed: 261,095,424 bytes (~249 MiB)

  // --- prep ---
  f32_to_bf16_vec<<<24576, 256, 0, stream>>>(x, xb);
  fill_bt1<<<3072, 256, 0, stream>>>(Bt1);
  fill_auv<<<19008, 256, 0, stream>>>(Au, Av);                  // 2304*2112/256
  transpose_f32_to_bf16<<<dim3(96, 24), 256, 0, stream>>>(W1, W1t, 768, 3072);
  transpose_f32_to_bf16<<<dim3(24, 96), 256, 0, stream>>>(W2, W2t, 3072, 768);

  // --- GEMM1: pack X @ [C_D|S_D] directly into BtU/BtV; 256x8 = 2048 blocks ---
  gemm128<0><<<2048, 256, 0, stream>>>(
      xb, Bt1, nullptr, nullptr, 768, 768, 768, 0L, 0L, 999, 256, 8,
      nullptr, BtUV, nullptr, nullptr, nullptr, 0);

  // --- fold_s: BtUV (K=4096) -> BtUVf (K=2112); 4096 rows = 8 batches x 512 d ---
  fold_s<<<4096, 256, 0, stream>>>(BtUV, BtUVf);

  // --- GEMM_uv fused (z<8: u = C_S' @ Tc' -> u_b; z>=8: v = S_S' @ Ts' -> v_b);
  //     K=2112, 18x4x16 = 1152 blocks, bf16 outputs ---
  gemm128<1><<<1152, 256, 0, stream>>>(
      Au, BtUVf, Av, BtUVf + 8650752L, 2112, 2112, 2112,
      512L * 2112L, 2304L * 512L, 8, 18, 4,
      nullptr, u_b, v_b, nullptr, nullptr, 512);

  // --- combine quadrants + xb residual + LN1 -> out1 (bf16), fused ---
  combine_ln<<<dim3(2049, 8), 256, 0, stream>>>(u_b, v_b, xb, g1, be1, o1b);

  // --- GEMM3: H = gelu(out1 @ W1 + b1); 256x24 = 6144 blocks ---
  gemm128<2><<<6144, 256, 0, stream>>>(
      o1b, W1t, nullptr, nullptr, 768, 768, 768, 0L, 0L, 999, 256, 24,
      nullptr, H, nullptr, b1, nullptr, 3072);

  // --- GEMM4: y2 = H @ W2 + b2 + out1 -> d_out; 256x6 = 1536 blocks ---
  gemm128<3><<<1536, 256, 0, stream>>>(
      H, W2t, nullptr, nullptr, 3072, 3072, 3072, 0L, 0L, 999, 256, 6,
      out, nullptr, nullptr, b2, o1b, 768);

  // --- LN2 in-place ---
  ln_row_f32<<<32768, 256, 0, stream>>>(out, g2, be2, out);
}

// Round 13
// 659.436 us; speedup vs baseline: 1.8501x; 1.0113x over previous
//
#include <hip/hip_runtime.h>
#include <cstdint>

// FNet block on MI355X.
//   attn = Re(FFT2(x)) via bf16 MFMA matmuls + real-input quadrant symmetry:
//     GEMM1: T = X @ [C_D | S_D], epilogue packs DIRECTLY into BtU/BtV [b][d][s]
//     fold_s: K-axis symmetry fold (cos even / sin odd about s=2048) -> K=2112
//     GEMM_uv (fused, z=0..15): u (cos) / v (sin), M=2176(pad), N=512, K=2112
//     combine_ln: quadrant-combine u+-v (bf16), + xb residual (bf16),
//            fused row-LayerNorm -> out1 bf16
//   GEMM3: H = gelu(out1 @ W1 + b1)       (M=32768, N=3072, K=768)  [fast tanh-gelu]
//   GEMM4: y2 = H @ W2 + b2 + out1        (M=32768, N=768, K=3072)
//   LN2 in-place on d_out.
//
// GEMM core (unchanged from rounds 9-12, verified): 128x128 tile, BK=64, 4 waves,
// single 32 KiB LDS buffer, 2 barriers/K-tile, T2 swizzle (0 bank conflicts),
// gload_lds 16B staging, XCD-gather 1D grid.
// NEW (round 13): N-GROUP decode (NYG,NG): co-resident blocks span only NYG
// B-panels so the B working set fits the 4 MB per-XCD L2. GEMM3 uses NYG=12,
// NG=2 (kills the measured 300-375 MB W1t L2-thrash; o1b read 2x = +50 MB).
// All other GEMMs use NG=1 (decode identical to round 12).

typedef __attribute__((ext_vector_type(8))) short short8;
typedef __attribute__((ext_vector_type(4))) float f32x4;

__device__ __forceinline__ unsigned short f2b(float f) {
  union { float f; uint32_t u; } c; c.f = f;
  uint32_t u = c.u;
  u += 0x7FFFu + ((u >> 16) & 1u);   // round-to-nearest-even
  return (unsigned short)(u >> 16);
}
__device__ __forceinline__ float b2f(unsigned short h) {
  union { uint32_t u; float f; } c; c.u = ((uint32_t)h) << 16;
  return c.f;
}

// fast GELU (tanh form), ~9 VALU. max |err vs exact erf-gelu| ~3e-3.
__device__ __forceinline__ float gelu_fast(float x) {
  float x2 = x * x;
  float inner = x * fmaf(x2, 0.0356774081f, 0.7978845608f);
  float zz = fminf(inner * 2.885390082f, 80.0f);   // exp2 arg = 2*inner*log2(e)
  float E, r;
  asm("v_exp_f32 %0, %1" : "=v"(E) : "v"(zz));
  float den = E + 1.0f;
  asm("v_rcp_f32 %0, %1" : "=v"(r) : "v"(den));
  return x * E * r;
}

// ---------------------------------------------------------------------------
// Fill / convert kernels
// ---------------------------------------------------------------------------

__global__ __launch_bounds__(256) void f32_to_bf16_vec(
    const float* __restrict__ in, unsigned short* __restrict__ out) {
  long i = (long)blockIdx.x * 256 + threadIdx.x;   // element-of-4 index
  float4 v = reinterpret_cast<const float4*>(in)[i];
  ushort4 o;
  o.x = f2b(v.x); o.y = f2b(v.y); o.z = f2b(v.z); o.w = f2b(v.w);
  reinterpret_cast<ushort4*>(out)[i] = o;
}

// Bt1: (1024 x 768). Row j<512: cos(2*pi*j*n/768); row j>=512: sin(2*pi*(j-512)*n/768).
__global__ __launch_bounds__(256) void fill_bt1(unsigned short* __restrict__ Bt1) {
  int i = blockIdx.x * 256 + threadIdx.x;          // < 1024*768
  int j = i / 768;
  int n = i - j * 768;
  int jj = j & 511;
  int m = (jj * n) % 768;
  float ang = (float)m * (6.283185307179586f / 768.0f);
  Bt1[i] = f2b((j < 512) ? cosf(ang) : sinf(ang));
}

// Au[k][s'] = cos(2*pi*k*s'/4096), Av[k][s'] = sin(...), k=0..2175, s'=0..2111.
__global__ __launch_bounds__(256) void fill_auv(
    unsigned short* __restrict__ Au, unsigned short* __restrict__ Av) {
  long i = (long)blockIdx.x * 256 + threadIdx.x;   // < 2176*2112
  if (i >= 2176L * 2112L) return;
  int k = (int)(i / 2112);
  int s = (int)(i - (long)k * 2112);
  int mm = (k * s) & 4095;
  float ang = (float)mm * (6.283185307179586f / 4096.0f);
  Au[i] = f2b(cosf(ang));
  Av[i] = f2b(sinf(ang));
}

// out[c][r] = bf16(in[r][c]); R,C multiples of 32  (for W1, W2)
__global__ __launch_bounds__(256) void transpose_f32_to_bf16(
    const float* __restrict__ in, unsigned short* __restrict__ out, int R, int C) {
  __shared__ float tile[32][33];
  const int c0 = blockIdx.x * 32;
  const int r0 = blockIdx.y * 32;
  const int tx = threadIdx.x & 31;
  const int ty = threadIdx.x >> 5;   // 0..7
#pragma unroll
  for (int i = ty; i < 32; i += 8)
    tile[i][tx] = in[(long)(r0 + i) * C + c0 + tx];
  __syncthreads();
#pragma unroll
  for (int i = ty; i < 32; i += 8)
    out[(long)(c0 + i) * R + r0 + tx] = f2b(tile[tx][i]);
}

// ---------------------------------------------------------------------------
// fold_s: per (b,d) row, fold s-axis symmetry of the length-4096 DFT.
//   Uf[s'] = U[s'] + U[4096-s'] (1<=s'<=2047); Uf[0]=U[0]; Uf[2048]=U[2048];
//   Vf[s'] = V[s'] - V[4096-s'] (1<=s'<=2047); Vf[0]=Vf[2048]=0;  pad->2112 zeros.
// EXACTLY 4096 rows (8 batches x 512 d). One block per row.
// ---------------------------------------------------------------------------
__global__ __launch_bounds__(256) void fold_s(
    const unsigned short* __restrict__ BtUV, unsigned short* __restrict__ BtUVf) {
  const long row = blockIdx.x;          // 0..4095
  const unsigned short* U = BtUV + (row << 12);
  const unsigned short* V = BtUV + 16777216L + (row << 12);
  unsigned short* Uf = BtUVf + row * 2112;
  unsigned short* Vf = BtUVf + 8650752L + row * 2112;
  for (int s = threadIdx.x; s < 2112; s += 256) {
    float uo, vo;
    if (s == 0)        { uo = b2f(U[0]);    vo = 0.f; }
    else if (s < 2048) { uo = b2f(U[s]) + b2f(U[4096 - s]);
                         vo = b2f(V[s]) - b2f(V[4096 - s]); }
    else if (s == 2048){ uo = b2f(U[2048]); vo = 0.f; }
    else               { uo = 0.f;          vo = 0.f; }
    Uf[s] = f2b(uo);
    Vf[s] = f2b(vo);
  }
}

// ---------------------------------------------------------------------------
// GEMM128: C = A (MxK row-major bf16) @ Bt^T (Bt NxK row-major bf16)
// 128x128 tile, BK=64, 256 threads (4 waves, 2x2), per-wave 64x64, acc[4][4].
// Single 32 KiB LDS buffer, 2 syncthreads/K-tile. T2 swizzle.
// 1D grid, XCD-gather remap (grid % 8 == 0) + N-GROUP decode:
//   l = (p%8)*(total/8)+p/8;
//   byg = l%NYG; bx = (l/NYG)%NX; g = (l/(NYG*NX))%NG; zz = l/(NYG*NX*NG);
//   by = g*NYG + byg.   (NG=1 reproduces the round-12 by-fastest decode.)
// Epilogues:
//   0 = pack into BtUV: col<512 -> U[b][col][s], col>=512 -> V[b][col-512][s]
//   1 = bf16 z-batched store; z>=zSplit switches operands (A2p,Bt2p,outB2)
//   2 = +bias, fast gelu, bf16 (GEMM3->H)
//   3 = +bias +bf16 residual, fp32 (GEMM4->y2)
// M,N multiples of 128; K multiple of 64.
// ---------------------------------------------------------------------------

template <int EPI>
__global__ __launch_bounds__(256, 3) void gemm128(
    const unsigned short* __restrict__ A, const unsigned short* __restrict__ Bt,
    const unsigned short* __restrict__ A2p, const unsigned short* __restrict__ Bt2p,
    int K, int lda, int ldb, long bBatch, long oBatch, int zSplit,
    int NX, int NYG, int NG,
    float* __restrict__ outF,
    unsigned short* __restrict__ outB, unsigned short* __restrict__ outB2,
    const float* __restrict__ bias, const unsigned short* __restrict__ residB,
    int ldOut) {
  __shared__ __align__(16) unsigned short As[128 * 64];   // 16 KB
  __shared__ __align__(16) unsigned short Bs[128 * 64];   // 16 KB

  const int tid = threadIdx.x;
  const int lane = tid & 63;
  const int wave = tid >> 6;         // 0..3
  const int wr = wave >> 1;          // 0..1
  const int wc = wave & 1;           // 0..1

  // ---- XCD-gather remap + N-group decode ----
  const int p = (int)blockIdx.x;
  const int l = (p & 7) * ((int)gridDim.x >> 3) + (p >> 3);
  int rem = l;
  const int byg = rem % NYG; rem /= NYG;
  const int bx  = rem % NX;  rem /= NX;
  const int g   = rem % NG;  rem /= NG;
  int zz = rem;
  const int by = g * NYG + byg;

  const unsigned short* Ax = A;
  const unsigned short* Bx = Bt;
  unsigned short* oB = outB;
  if (EPI == 1 && zz >= zSplit) { Ax = A2p; Bx = Bt2p; oB = outB2; zz -= zSplit; }

  const unsigned short* Ab = Ax + (long)bx * 128 * lda;
  const unsigned short* Bb = Bx + (long)zz * bBatch + (long)by * 128 * ldb;

  const int NT = K >> 6;             // #K-tiles

  // Staging: linear LDS dest, T2 swizzle pre-applied to per-lane GLOBAL column.
  const int srow = lane >> 3;                      // 0..7
  const int scolE = ((lane & 7) ^ srow) << 3;      // pre-swizzled col (elems)

  const int fr = lane & 15;          // frag row within 16
  const int fkB = (lane >> 4) << 4;  // byte k-offset within 32-k half (0,16,32,48)
  const int fxor = (lane & 7) << 4;  // T2 swizzle XOR (row&7 == lane&7 for frag rows)

  f32x4 acc[4][4] = {};

  for (int t = 0; t < NT; ++t) {
    // ---- stage tile t: 16 chunks of 8 rows; wave w does chunks i*4+w ----
#pragma unroll
    for (int i_ = 0; i_ < 4; ++i_) {
      const int chunk = i_ * 4 + wave;             // wave-uniform
      const int row = chunk * 8 + srow;
      __builtin_amdgcn_global_load_lds(
          (const __attribute__((address_space(1))) void*)(Ab + (long)row * lda + (long)t * 64 + scolE),
          (__attribute__((address_space(3))) void*)(As + chunk * 512), 16, 0, 0);
      __builtin_amdgcn_global_load_lds(
          (const __attribute__((address_space(1))) void*)(Bb + (long)row * ldb + (long)t * 64 + scolE),
          (__attribute__((address_space(3))) void*)(Bs + chunk * 512), 16, 0, 0);
    }
    __syncthreads();   // drains vmcnt (gload_lds) — data visible to all waves

    const char* Ap = reinterpret_cast<const char*>(As);
    const char* Bp = reinterpret_cast<const char*>(Bs);
#pragma unroll
    for (int ks = 0; ks < 2; ++ks) {
      short8 af[4], bf[4];
#pragma unroll
      for (int mf = 0; mf < 4; ++mf) {
        const int row = wr * 64 + mf * 16 + fr;
        af[mf] = *reinterpret_cast<const short8*>(Ap + ((row * 128 + ks * 64 + fkB) ^ fxor));
      }
#pragma unroll
      for (int nf = 0; nf < 4; ++nf) {
        const int row = wc * 64 + nf * 16 + fr;
        bf[nf] = *reinterpret_cast<const short8*>(Bp + ((row * 128 + ks * 64 + fkB) ^ fxor));
      }
#pragma unroll
      for (int mf = 0; mf < 4; ++mf)
#pragma unroll
        for (int nf = 0; nf < 4; ++nf)
          acc[mf][nf] = __builtin_amdgcn_mfma_f32_16x16x32_bf16(
              af[mf], bf[nf], acc[mf][nf], 0, 0, 0);
    }
    __syncthreads();   // all waves done reading before next stage overwrites
  }

  // Epilogue. C/D layout: col = lane&15, row = (lane>>4)*4 + reg  [m89/m91]
  const long rowBase = (long)bx * 128 + wr * 64 + ((lane >> 4) << 2);
  const int colBase = by * 128 + wc * 64 + (lane & 15);
#pragma unroll
  for (int mf = 0; mf < 4; ++mf) {
#pragma unroll
    for (int nf = 0; nf < 4; ++nf) {
      const int col = colBase + nf * 16;
#pragma unroll
      for (int i = 0; i < 4; ++i) {
        const long r = rowBase + mf * 16 + i;
        float vv = acc[mf][nf][i];
        if constexpr (EPI == 0) {
          // pack T[r][col] -> BtUV: half = col>>9, d = col&511, b = r>>12, s = r&4095
          const long dst = (long)(col >> 9) * 16777216L +
                           ((((long)(r >> 12) << 9) + (col & 511)) << 12) + (r & 4095);
          outB[dst] = f2b(vv);
        } else if constexpr (EPI == 1) {
          oB[(long)zz * oBatch + r * (long)ldOut + col] = f2b(vv);
        } else if constexpr (EPI == 2) {
          outB[r * (long)ldOut + col] = f2b(gelu_fast(vv + bias[col]));
        } else {
          const long idx = r * (long)ldOut + col;
          outF[idx] = vv + bias[col] + b2f(residB[idx]);
        }
      }
    }
  }
}

// ---------------------------------------------------------------------------
// combine_ln: quadrant combine (bf16 u,v) + xb residual (bf16) + row LayerNorm.
// Block (k,z) owns FULL rows k and 4096-k; writes out1 bf16 directly.
// u/v row stride is 2176 (padded M of GEMM_uv).
// ---------------------------------------------------------------------------
__global__ __launch_bounds__(256) void combine_ln(
    const unsigned short* __restrict__ u, const unsigned short* __restrict__ v,
    const unsigned short* __restrict__ xb, const float* __restrict__ gamma,
    const float* __restrict__ beta, unsigned short* __restrict__ o1b) {
  const int k = blockIdx.x;            // 0..2048
  const int z = blockIdx.y;            // 0..7
  const long ub = ((long)z * 2176 + k) * 512;
  const long base = (long)z * 4096L * 768;
  const long rowA = base + (long)k * 768;
  const long rowB = base + (long)(4096 - k) * 768;
  const bool doRowB = (k != 0) && (k != 2048);
  const int t = threadIdx.x;

  float vA0[2], vA1[2], vB0[2], vB1[2];
  float sA = 0.f, qA = 0.f, sB = 0.f, qB = 0.f;
#pragma unroll
  for (int it = 0; it < 2; ++it) {
    const int d = t + it * 256;
    if (d <= 384) {
      const float uu = b2f(u[ub + d]);
      const float vv = b2f(v[ub + d]);
      const float a1 = uu - vv;
      const float a2 = uu + vv;
      const int dd = 768 - d;
      const bool colB = (d != 0) && (d != 384);
      float va = a1 + b2f(xb[rowA + d]);
      vA0[it] = va; sA += va; qA += va * va;
      if (colB) { float w = a2 + b2f(xb[rowA + dd]); vA1[it] = w; sA += w; qA += w * w; }
      if (doRowB) {
        float wb = a2 + b2f(xb[rowB + d]);
        vB0[it] = wb; sB += wb; qB += wb * wb;
        if (colB) { float w2 = a1 + b2f(xb[rowB + dd]); vB1[it] = w2; sB += w2; qB += w2 * w2; }
      }
    }
  }
#pragma unroll
  for (int off = 32; off > 0; off >>= 1) {
    sA += __shfl_down(sA, off, 64); qA += __shfl_down(qA, off, 64);
    sB += __shfl_down(sB, off, 64); qB += __shfl_down(qB, off, 64);
  }
  __shared__ float red[4][4];
  if ((t & 63) == 0) {
    red[t >> 6][0] = sA; red[t >> 6][1] = qA;
    red[t >> 6][2] = sB; red[t >> 6][3] = qB;
  }
  __syncthreads();
  const float SA = red[0][0] + red[1][0] + red[2][0] + red[3][0];
  const float QA = red[0][1] + red[1][1] + red[2][1] + red[3][1];
  const float SB = red[0][2] + red[1][2] + red[2][2] + red[3][2];
  const float QB = red[0][3] + red[1][3] + red[2][3] + red[3][3];
  const float muA = SA * (1.0f / 768.0f);
  const float rsA = rsqrtf(QA * (1.0f / 768.0f) - muA * muA + 1e-6f);
  const float muB = SB * (1.0f / 768.0f);
  const float rsB = rsqrtf(QB * (1.0f / 768.0f) - muB * muB + 1e-6f);

#pragma unroll
  for (int it = 0; it < 2; ++it) {
    const int d = t + it * 256;
    if (d <= 384) {
      const int dd = 768 - d;
      const bool colB = (d != 0) && (d != 384);
      const float g0 = gamma[d], b0 = beta[d];
      o1b[rowA + d] = f2b((vA0[it] - muA) * rsA * g0 + b0);
      if (colB) o1b[rowA + dd] = f2b((vA1[it] - muA) * rsA * gamma[dd] + beta[dd]);
      if (doRowB) {
        o1b[rowB + d] = f2b((vB0[it] - muB) * rsB * g0 + b0);
        if (colB) o1b[rowB + dd] = f2b((vB1[it] - muB) * rsB * gamma[dd] + beta[dd]);
      }
    }
  }
}

// ---------------------------------------------------------------------------
// Row LayerNorm over D=768 (fp32 in/out, used for LN2 in-place).
// ---------------------------------------------------------------------------
__global__ __launch_bounds__(256) void ln_row_f32(
    const float* __restrict__ in, const float* __restrict__ gamma,
    const float* __restrict__ beta, float* __restrict__ outF) {
  const long row = blockIdx.x;
  const float* p = in + row * 768;
  const int t = threadIdx.x;
  const float v0 = p[t], v1 = p[t + 256], v2 = p[t + 512];
  float s = v0 + v1 + v2;
  float q = v0 * v0 + v1 * v1 + v2 * v2;
#pragma unroll
  for (int off = 32; off > 0; off >>= 1) {
    s += __shfl_down(s, off, 64);
    q += __shfl_down(q, off, 64);
  }
  __shared__ float ss[4], sq[4];
  if ((t & 63) == 0) { ss[t >> 6] = s; sq[t >> 6] = q; }
  __syncthreads();
  const float S = ss[0] + ss[1] + ss[2] + ss[3];
  const float Q = sq[0] + sq[1] + sq[2] + sq[3];
  const float mu = S * (1.0f / 768.0f);
  const float var = Q * (1.0f / 768.0f) - mu * mu;
  const float rs = rsqrtf(var + 1e-6f);
  outF[row * 768 + t]       = (v0 - mu) * rs * gamma[t] + beta[t];
  outF[row * 768 + t + 256] = (v1 - mu) * rs * gamma[t + 256] + beta[t + 256];
  outF[row * 768 + t + 512] = (v2 - mu) * rs * gamma[t + 512] + beta[t + 512];
}

// ---------------------------------------------------------------------------

extern "C" void kernel_launch(void* const* d_in, const int* in_sizes, int n_in,
                              void* d_out, int out_size, void* d_ws, size_t ws_size,
                              hipStream_t stream) {
  const float* x   = (const float*)d_in[0];   // (8,4096,768)
  const float* W1  = (const float*)d_in[1];   // (768,3072)
  const float* b1  = (const float*)d_in[2];   // (3072)
  const float* W2  = (const float*)d_in[3];   // (3072,768)
  const float* b2  = (const float*)d_in[4];   // (768)
  const float* g1  = (const float*)d_in[5];
  const float* be1 = (const float*)d_in[6];
  const float* g2  = (const float*)d_in[7];
  const float* be2 = (const float*)d_in[8];
  float* out = (float*)d_out;                 // fp32, also y2 scratch

  char* ws = (char*)d_ws;
  unsigned short* xb    = (unsigned short*)(ws + 0L);           //  50,331,648 (live until combine_ln)
  unsigned short* Bt1   = (unsigned short*)(ws + 50331648L);    //   1,572,864
  unsigned short* Au    = (unsigned short*)(ws + 51904512L);    //   9,191,424 (2176x2112)
  unsigned short* Av    = (unsigned short*)(ws + 61636608L);    //   9,191,424
  unsigned short* u_b   = (unsigned short*)(ws + 71368704L);    //  17,825,792 (8x2176x512)
  unsigned short* v_b   = (unsigned short*)(ws + 90243072L);    //  17,825,792
  unsigned short* BtUVf = (unsigned short*)(ws + 109117440L);   //  34,603,008 -> ends 143,720,448
  unsigned short* BtUV  = (unsigned short*)(ws + 156762112L);   //  67,108,864 -> ends 223,870,976 (dead after fold_s)
  unsigned short* H     = (unsigned short*)(ws + 0L);           // 201,326,592 (aliases everything below o1b; all dead by GEMM3)
  unsigned short* o1b   = (unsigned short*)(ws + 201326592L);   //  50,331,648 (overlaps dead BtUV tail)
  unsigned short* W1t   = (unsigned short*)(ws + 251658240L);   //   4,718,592
  unsigned short* W2t   = (unsigned short*)(ws + 256376832L);   //   4,718,592
  // total ws needed: 261,095,424 bytes (~249 MiB)

  // --- prep ---
  f32_to_bf16_vec<<<24576, 256, 0, stream>>>(x, xb);
  fill_bt1<<<3072, 256, 0, stream>>>(Bt1);
  fill_auv<<<17952, 256, 0, stream>>>(Au, Av);                  // 2176*2112/256
  transpose_f32_to_bf16<<<dim3(96, 24), 256, 0, stream>>>(W1, W1t, 768, 3072);
  transpose_f32_to_bf16<<<dim3(24, 96), 256, 0, stream>>>(W2, W2t, 3072, 768);

  // --- GEMM1: pack X @ [C_D|S_D] directly into BtU/BtV; 256x8 = 2048 blocks ---
  gemm128<0><<<2048, 256, 0, stream>>>(
      xb, Bt1, nullptr, nullptr, 768, 768, 768, 0L, 0L, 999, 256, 8, 1,
      nullptr, BtUV, nullptr, nullptr, nullptr, 0);

  // --- fold_s: BtUV (K=4096) -> BtUVf (K=2112); 4096 rows = 8 batches x 512 d ---
  fold_s<<<4096, 256, 0, stream>>>(BtUV, BtUVf);

  // --- GEMM_uv fused (z<8: u -> u_b; z>=8: v -> v_b); M=2176, K=2112,
  //     17x4x16 = 1088 blocks, bf16 outputs ---
  gemm128<1><<<1088, 256, 0, stream>>>(
      Au, BtUVf, Av, BtUVf + 8650752L, 2112, 2112, 2112,
      512L * 2112L, 2176L * 512L, 8, 17, 4, 1,
      nullptr, u_b, v_b, nullptr, nullptr, 512);

  // --- combine quadrants + xb residual + LN1 -> out1 (bf16), fused ---
  combine_ln<<<dim3(2049, 8), 256, 0, stream>>>(u_b, v_b, xb, g1, be1, o1b);

  // --- GEMM3: H = gelu(out1 @ W1 + b1); NYG=12, NG=2 -> 256x12x2 = 6144 blocks ---
  gemm128<2><<<6144, 256, 0, stream>>>(
      o1b, W1t, nullptr, nullptr, 768, 768, 768, 0L, 0L, 999, 256, 12, 2,
      nullptr, H, nullptr, b1, nullptr, 3072);

  // --- GEMM4: y2 = H @ W2 + b2 + out1 -> d_out; 256x6 = 1536 blocks ---
  gemm128<3><<<1536, 256, 0, stream>>>(
      H, W2t, nullptr, nullptr, 3072, 3072, 3072, 0L, 0L, 999, 256, 6, 1,
      out, nullptr, nullptr, b2, o1b, 768);

  // --- LN2 in-place ---
  ln_row_f32<<<32768, 256, 0, stream>>>(out, g2, be2, out);
}